// Round 4
// baseline (1628.071 us; speedup 1.0000x reference)
//
#include <hip/hip_runtime.h>
#include <hip/hip_fp16.h>
#include <math.h>

#define NN 131072
#define NE 2097152
#define NG 16384

__device__ __forceinline__ float lrelu(float x, float s) { return x > 0.f ? x : s * x; }

template <int H>
__device__ __forceinline__ float sel_h(const float* a, int hsel) {
    if constexpr (H == 1) return a[0];
    else return hsel == 0 ? a[0] : hsel == 1 ? a[1] : hsel == 2 ? a[2] : a[3];
}

// ---------------- CSR build ----------------
__global__ void k_hist(const int* __restrict__ dst, int* __restrict__ cnt) {
    int e = blockIdx.x * 256 + threadIdx.x;
    if (e < NE) atomicAdd(&cnt[dst[e]], 1);
}

__global__ void k_scan1(const int* __restrict__ cnt, int* __restrict__ rowptr, int* __restrict__ part) {
    __shared__ int s[256];
    int t = threadIdx.x;
    int i = blockIdx.x * 256 + t;
    int v = cnt[i];
    s[t] = v;
    __syncthreads();
    for (int off = 1; off < 256; off <<= 1) {
        int x = (t >= off) ? s[t - off] : 0;
        __syncthreads();
        s[t] += x;
        __syncthreads();
    }
    rowptr[i] = s[t] - v;  // exclusive
    if (t == 255) part[blockIdx.x] = s[255];
}

__global__ void k_scan2(int* part) {
    __shared__ int s[512];
    int t = threadIdx.x;
    int v = part[t];
    s[t] = v;
    __syncthreads();
    for (int off = 1; off < 512; off <<= 1) {
        int x = (t >= off) ? s[t - off] : 0;
        __syncthreads();
        s[t] += x;
        __syncthreads();
    }
    part[t] = s[t] - v;  // exclusive
}

__global__ void k_scan3(int* __restrict__ rowptr, const int* __restrict__ part, int* __restrict__ cursor) {
    int t = threadIdx.x;
    int i = blockIdx.x * 256 + t;
    int v = rowptr[i] + part[blockIdx.x];
    rowptr[i] = v;
    cursor[i] = v;
    if (i == 0) rowptr[NN] = NE;
}

__global__ void k_scatter(const int* __restrict__ dst, int* __restrict__ cursor, int* __restrict__ perm) {
    int e = blockIdx.x * 256 + threadIdx.x;
    if (e < NE) {
        int p = atomicAdd(&cursor[dst[e]], 1);
        perm[p] = e;
    }
}

// ---------------- node transform + fused alpha projections ----------------
// h = in @ W (fp16 out, zero-padded to FSO); alpha_s/d = per-head dot(h, a) via
// in-wave shuffle reduction (GRP = C if pow2, else whole wave).
template <int FIN, int F, int FP, int FSO, int H, int C>
__global__ void k_transform(const float* __restrict__ in, const float* __restrict__ W,
                            const float* __restrict__ as_, const float* __restrict__ ad_,
                            __half* __restrict__ h, float* __restrict__ alpha_s,
                            float* __restrict__ alpha_d) {
    constexpr int BN = 256 / FP;
    constexpr int GRP = ((C & (C - 1)) == 0) ? C : 64;
    __shared__ float Wl[FIN * F];
    __shared__ float xl[BN * FIN];
    int t = threadIdx.x;
    for (int i = t; i < FIN * F; i += 256) Wl[i] = W[i];
    int nb = blockIdx.x * BN;
    for (int i = t; i < BN * FIN; i += 256) xl[i] = in[(size_t)nb * FIN + i];
    __syncthreads();
    int nl = t / FP, f = t % FP;
    int n = nb + nl;
    float acc = 0.f;
    if (f < F) {
#pragma unroll
        for (int k = 0; k < FIN; k++) acc += xl[nl * FIN + k] * Wl[k * F + f];
        h[(size_t)n * FSO + f] = __float2half(acc);
    } else if (f < FSO) {
        h[(size_t)n * FSO + f] = __float2half(0.f);
    }
    float hs = (f < F) ? acc * as_[f] : 0.f;
    float hd = (f < F) ? acc * ad_[f] : 0.f;
#pragma unroll
    for (int off = 1; off < GRP; off <<= 1) {
        hs += __shfl_xor(hs, off);
        hd += __shfl_xor(hd, off);
    }
    if ((f % GRP) == 0 && f < F) {
        alpha_s[(size_t)n * H + f / GRP] = hs;
        alpha_d[(size_t)n * H + f / GRP] = hd;
    }
}

// ---------------- per-node softmax + aggregation (1 wave / node, 4 nodes / block) ----------------
// No max-pass: alpha is O(1) by construction (clamped at 80 for f32-exp safety);
// softmax ratios are identical. Phase 2: multi-edge/iter, uint2 gathers,
// v_readlane for src indices (no LDS for srcs).
template <int H, int C, bool FINAL>
__global__ __launch_bounds__(256) void k_aggregate(
    const __half* __restrict__ h, const float* __restrict__ asrc, const float* __restrict__ adst,
    const int* __restrict__ rowptr, const int* __restrict__ perm,
    const int* __restrict__ srcs, const float* __restrict__ ew,
    const float* __restrict__ We, const float* __restrict__ ae, const float* __restrict__ b,
    const float* __restrict__ bn_g, const float* __restrict__ bn_b,
    const float* __restrict__ bn_rm, const float* __restrict__ bn_rv,
    float* __restrict__ out) {
    constexpr int F = H * C;
    constexpr bool P2 = (F > 64);
    constexpr int FS = P2 ? 128 : 64;  // h row stride in halves
    constexpr int LPE = P2 ? 32 : 16;  // lanes per edge (uint2-granules per row)
    constexpr int EPI = 64 / LPE;      // edges per iteration (2 or 4)
    __shared__ float lds_att[4][(64 + EPI) * H];

    int wid = threadIdx.x >> 6;
    int lane = threadIdx.x & 63;
    int n = blockIdx.x * 4 + wid;
    int r0 = __builtin_amdgcn_readfirstlane(rowptr[n]);
    int r1 = __builtin_amdgcn_readfirstlane(rowptr[n + 1]);
    int deg = r1 - r0;

    // per-head constants
    float ce[H], ad[H];
#pragma unroll
    for (int hh = 0; hh < H; hh++) {
        float c = 0.f;
#pragma unroll
        for (int cc = 0; cc < C; cc++) c += We[hh * C + cc] * ae[hh * C + cc];
        ce[hh] = c;
    }
    if constexpr (H == 4) {
        float4 adv = ((const float4*)adst)[n];
        ad[0] = adv.x; ad[1] = adv.y; ad[2] = adv.z; ad[3] = adv.w;
    } else {
        ad[0] = adst[n];
    }

    // ---- phase 1: one edge per lane; exp(alpha) directly (no max pass) ----
    bool val = lane < deg;
    int s_l = 0;
    float w_l = 0.f;
    if (val) {
        int e = perm[r0 + lane];
        s_l = srcs[e];
        w_l = ew[e];
    }
    float ex_l[H], psum[H];
    if constexpr (H == 4) {
        if (val) {
            float4 v4 = ((const float4*)asrc)[s_l];
            ex_l[0] = __expf(fminf(lrelu(v4.x + ad[0] + w_l * ce[0], 0.2f), 80.f));
            ex_l[1] = __expf(fminf(lrelu(v4.y + ad[1] + w_l * ce[1], 0.2f), 80.f));
            ex_l[2] = __expf(fminf(lrelu(v4.z + ad[2] + w_l * ce[2], 0.2f), 80.f));
            ex_l[3] = __expf(fminf(lrelu(v4.w + ad[3] + w_l * ce[3], 0.2f), 80.f));
        } else {
            ex_l[0] = ex_l[1] = ex_l[2] = ex_l[3] = 0.f;
        }
    } else {
        ex_l[0] = val ? __expf(fminf(lrelu(asrc[s_l] + ad[0] + w_l * ce[0], 0.2f), 80.f)) : 0.f;
    }
#pragma unroll
    for (int hh = 0; hh < H; hh++) psum[hh] = ex_l[hh];
    // overflow edges (deg > 64, rare): add into denom
    for (int r = r0 + 64 + lane; r < r1; r += 64) {
        int e = perm[r];
        int s = srcs[e];
        float w = ew[e];
        if constexpr (H == 4) {
            float4 v4 = ((const float4*)asrc)[s];
            psum[0] += __expf(fminf(lrelu(v4.x + ad[0] + w * ce[0], 0.2f), 80.f));
            psum[1] += __expf(fminf(lrelu(v4.y + ad[1] + w * ce[1], 0.2f), 80.f));
            psum[2] += __expf(fminf(lrelu(v4.z + ad[2] + w * ce[2], 0.2f), 80.f));
            psum[3] += __expf(fminf(lrelu(v4.w + ad[3] + w * ce[3], 0.2f), 80.f));
        } else {
            psum[0] += __expf(fminf(lrelu(asrc[s] + ad[0] + w * ce[0], 0.2f), 80.f));
        }
    }
    float rden[H];
#pragma unroll
    for (int hh = 0; hh < H; hh++) {
        float v = psum[hh];
#pragma unroll
        for (int off = 32; off >= 1; off >>= 1) v += __shfl_xor(v, off);
        rden[hh] = 1.f / (v + 1e-16f);
    }

    // stage att = ex/den in LDS (+ zero pad for loop overrun)
#pragma unroll
    for (int hh = 0; hh < H; hh++) lds_att[wid][lane * H + hh] = ex_l[hh] * rden[hh];
    if (lane < EPI * H) lds_att[wid][64 * H + lane] = 0.f;
    __syncthreads();

    // ---- phase 2: EPI edges per iter, 4 features (uint2) per lane ----
    int jn = deg < 64 ? deg : 64;
    int flane = lane & (LPE - 1);
    int grp = lane / LPE;
    int f0 = 4 * flane;
    int hsel = (H == 1) ? 0 : (f0 / C);
    const uint2* h2 = (const uint2*)h;
    float a0 = 0.f, a1 = 0.f, a2 = 0.f, a3 = 0.f;
#pragma unroll 2
    for (int j = 0; j < jn; j += EPI) {
        int je = j + grp;
        float att = lds_att[wid][je * H + hsel];
        int s;
        if constexpr (EPI == 2) {
            int sA = __builtin_amdgcn_readlane(s_l, j);
            int sB = __builtin_amdgcn_readlane(s_l, j + 1);
            s = (grp == 0) ? sA : sB;
        } else {
            int sA = __builtin_amdgcn_readlane(s_l, j);
            int sB = __builtin_amdgcn_readlane(s_l, j + 1);
            int sC = __builtin_amdgcn_readlane(s_l, j + 2);
            int sD = __builtin_amdgcn_readlane(s_l, j + 3);
            s = (grp == 0) ? sA : (grp == 1) ? sB : (grp == 2) ? sC : sD;
        }
        uint2 p = h2[(size_t)s * (FS / 4) + flane];
        __half2 p01 = *(__half2*)&p.x;
        __half2 p23 = *(__half2*)&p.y;
        a0 = fmaf(__low2float(p01), att, a0);
        a1 = fmaf(__high2float(p01), att, a1);
        a2 = fmaf(__low2float(p23), att, a2);
        a3 = fmaf(__high2float(p23), att, a3);
    }
    if (deg > 64) {  // rare
        float rdensel = sel_h<H>(rden, hsel);
        for (int r = r0 + 64; r < r1; ++r) {
            int e = __builtin_amdgcn_readfirstlane(perm[r]);
            int s = __builtin_amdgcn_readfirstlane(srcs[e]);
            float w = ew[e];
            float aA[H];
            if constexpr (H == 4) {
                float4 v4 = ((const float4*)asrc)[s];
                aA[0] = fminf(lrelu(v4.x + ad[0] + w * ce[0], 0.2f), 80.f);
                aA[1] = fminf(lrelu(v4.y + ad[1] + w * ce[1], 0.2f), 80.f);
                aA[2] = fminf(lrelu(v4.z + ad[2] + w * ce[2], 0.2f), 80.f);
                aA[3] = fminf(lrelu(v4.w + ad[3] + w * ce[3], 0.2f), 80.f);
            } else {
                aA[0] = fminf(lrelu(asrc[s] + ad[0] + w * ce[0], 0.2f), 80.f);
            }
            float att = __expf(sel_h<H>(aA, hsel)) * rdensel;
            att = (grp == 0) ? att : 0.f;
            uint2 p = h2[(size_t)s * (FS / 4) + flane];
            __half2 p01 = *(__half2*)&p.x;
            __half2 p23 = *(__half2*)&p.y;
            a0 = fmaf(__low2float(p01), att, a0);
            a1 = fmaf(__high2float(p01), att, a1);
            a2 = fmaf(__low2float(p23), att, a2);
            a3 = fmaf(__high2float(p23), att, a3);
        }
    }

    // combine across edge groups
    a0 += __shfl_xor(a0, 32);
    a1 += __shfl_xor(a1, 32);
    a2 += __shfl_xor(a2, 32);
    a3 += __shfl_xor(a3, 32);
    if constexpr (!P2) {
        a0 += __shfl_xor(a0, 16);
        a1 += __shfl_xor(a1, 16);
        a2 += __shfl_xor(a2, 16);
        a3 += __shfl_xor(a3, 16);
    }

    if constexpr (P2) {
        if (lane < 32) {
            float4 o;
            o.x = lrelu(a0 + b[f0], 0.01f);
            o.y = lrelu(a1 + b[f0 + 1], 0.01f);
            o.z = lrelu(a2 + b[f0 + 2], 0.01f);
            o.w = lrelu(a3 + b[f0 + 3], 0.01f);
            ((float4*)out)[(size_t)n * 32 + lane] = o;
        }
    } else if constexpr (FINAL) {
        if (lane < 16 && f0 < 50) {
            float o[4] = {a0, a1, a2, a3};
#pragma unroll
            for (int k = 0; k < 4; k++) {
                int f = f0 + k;
                if (f < 50) {
                    float v = o[k] + b[f];
                    v = (v - bn_rm[f]) * rsqrtf(bn_rv[f] + 1e-5f) * bn_g[f] + bn_b[f];
                    o[k] = lrelu(v, 0.01f);
                }
            }
            if (f0 < 48) {
                ((float4*)(out + (size_t)n * 64 + f0))[0] = make_float4(o[0], o[1], o[2], o[3]);
            } else {
                ((float2*)(out + (size_t)n * 64 + 48))[0] = make_float2(o[0], o[1]);
            }
        }
    } else {
        if (lane < 16) {
            float4 o;
            o.x = lrelu(a0 + b[f0], 0.01f);
            o.y = lrelu(a1 + b[f0 + 1], 0.01f);
            o.z = lrelu(a2 + b[f0 + 2], 0.01f);
            o.w = lrelu(a3 + b[f0 + 3], 0.01f);
            ((float4*)out)[(size_t)n * 16 + lane] = o;
        }
    }
}

// ---------------- graph pooling: segment-sum via sorted batch (binary search) ----------------
__global__ __launch_bounds__(256) void k_pool(const float* __restrict__ nodeout, const int* __restrict__ batch,
                                              float* __restrict__ gbuf) {
    int wid = threadIdx.x >> 6;
    int lane = threadIdx.x & 63;
    int g = blockIdx.x * 4 + wid;
    int lo = 0, hi = NN;
    while (lo < hi) {
        int mid = (lo + hi) >> 1;
        if (batch[mid] < g) lo = mid + 1; else hi = mid;
    }
    int s0 = lo;
    hi = NN;
    while (lo < hi) {
        int mid = (lo + hi) >> 1;
        if (batch[mid] < g + 1) lo = mid + 1; else hi = mid;
    }
    int s1 = lo;
    if (lane < 50) {
        float acc = 0.f;
        for (int n = s0; n < s1; ++n) acc += nodeout[(size_t)n * 64 + lane];
        gbuf[(size_t)g * 50 + lane] = acc;
    }
}

// ---------------- final MLP over graphs ----------------
__global__ void k_mlp(const float* __restrict__ gbuf,
                      const float* __restrict__ Wf1, const float* __restrict__ bf1,
                      const float* __restrict__ Wf2, const float* __restrict__ bf2,
                      const float* __restrict__ Wf3, const float* __restrict__ bf3,
                      float* __restrict__ out) {
    __shared__ float W1[1500], W2[600], W3[40], B1[30], B2[20], B3[2];
    int t = threadIdx.x;
    for (int i = t; i < 1500; i += 256) W1[i] = Wf1[i];
    for (int i = t; i < 600; i += 256) W2[i] = Wf2[i];
    for (int i = t; i < 40; i += 256) W3[i] = Wf3[i];
    if (t < 30) B1[t] = bf1[t];
    if (t < 20) B2[t] = bf2[t];
    if (t < 2) B3[t] = bf3[t];
    __syncthreads();
    int g = blockIdx.x * 256 + t;
    float gv[50];
#pragma unroll
    for (int i = 0; i < 50; i++) gv[i] = gbuf[(size_t)g * 50 + i];
    float h1[30];
#pragma unroll
    for (int j = 0; j < 30; j++) {
        float a = B1[j];
#pragma unroll
        for (int i = 0; i < 50; i++) a += gv[i] * W1[i * 30 + j];
        h1[j] = lrelu(a, 0.01f);
    }
    float h2[20];
#pragma unroll
    for (int j = 0; j < 20; j++) {
        float a = B2[j];
#pragma unroll
        for (int i = 0; i < 30; i++) a += h1[i] * W2[i * 20 + j];
        h2[j] = lrelu(a, 0.01f);
    }
#pragma unroll
    for (int j = 0; j < 2; j++) {
        float a = B3[j];
#pragma unroll
        for (int i = 0; i < 20; i++) a += h2[i] * W3[i * 2 + j];
        out[(size_t)g * 2 + j] = a;
    }
}

extern "C" void kernel_launch(void* const* d_in, const int* in_sizes, int n_in,
                              void* d_out, int out_size, void* d_ws, size_t ws_size,
                              hipStream_t stream) {
    const float* x = (const float*)d_in[0];
    const int* ei = (const int*)d_in[1];
    const float* ew = (const float*)d_in[2];
    const int* batch = (const int*)d_in[3];
    const float* W1 = (const float*)d_in[4];
    const float* as1 = (const float*)d_in[5];
    const float* ad1 = (const float*)d_in[6];
    const float* We1 = (const float*)d_in[7];
    const float* ae1 = (const float*)d_in[8];
    const float* b1 = (const float*)d_in[9];
    const float* W2 = (const float*)d_in[10];
    const float* as2 = (const float*)d_in[11];
    const float* ad2 = (const float*)d_in[12];
    const float* We2 = (const float*)d_in[13];
    const float* ae2 = (const float*)d_in[14];
    const float* b2 = (const float*)d_in[15];
    const float* W3 = (const float*)d_in[16];
    const float* as3 = (const float*)d_in[17];
    const float* ad3 = (const float*)d_in[18];
    const float* We3 = (const float*)d_in[19];
    const float* ae3 = (const float*)d_in[20];
    const float* b3 = (const float*)d_in[21];
    const float* W4 = (const float*)d_in[22];
    const float* as4 = (const float*)d_in[23];
    const float* ad4 = (const float*)d_in[24];
    const float* We4 = (const float*)d_in[25];
    const float* ae4 = (const float*)d_in[26];
    const float* b4 = (const float*)d_in[27];
    const float* bn_g = (const float*)d_in[28];
    const float* bn_b = (const float*)d_in[29];
    const float* bn_rm = (const float*)d_in[30];
    const float* bn_rv = (const float*)d_in[31];
    const float* Wf1 = (const float*)d_in[32];
    const float* bf1 = (const float*)d_in[33];
    const float* Wf2 = (const float*)d_in[34];
    const float* bf2 = (const float*)d_in[35];
    const float* Wf3 = (const float*)d_in[36];
    const float* bf3 = (const float*)d_in[37];
    float* out = (float*)d_out;

    const int* src = ei;
    const int* dst = ei + NE;

    // workspace layout
    char* ws = (char*)d_ws;
    float* feat = (float*)ws;   ws += (size_t)NN * 128 * 4;  // 64 MB (f32 activations / layer-4 node out)
    __half* hbuf = (__half*)ws; ws += (size_t)NN * 128 * 2;  // 32 MB (fp16 transformed h)
    float* as_buf = (float*)ws; ws += (size_t)NN * 4 * 4;
    float* ad_buf = (float*)ws; ws += (size_t)NN * 4 * 4;
    int* cnt = (int*)ws;        ws += (size_t)NN * 4;
    int* rowptr = (int*)ws;     ws += (size_t)(NN + 64) * 4;
    int* cursor = (int*)ws;     ws += (size_t)NN * 4;
    int* perm = (int*)ws;       ws += (size_t)NE * 4;
    int* part = (int*)ws;       ws += 512 * 4;
    float* gbuf = (float*)ws;   ws += (size_t)NG * 50 * 4;

    // CSR build
    hipMemsetAsync(cnt, 0, (size_t)NN * 4, stream);
    k_hist<<<NE / 256, 256, 0, stream>>>(dst, cnt);
    k_scan1<<<NN / 256, 256, 0, stream>>>(cnt, rowptr, part);
    k_scan2<<<1, 512, 0, stream>>>(part);
    k_scan3<<<NN / 256, 256, 0, stream>>>(rowptr, part, cursor);
    k_scatter<<<NE / 256, 256, 0, stream>>>(dst, cursor, perm);

    // layer 1: fin=6, H=4, C=16 (F=64)
    k_transform<6, 64, 64, 64, 4, 16><<<NN / 4, 256, 0, stream>>>(x, W1, as1, ad1, hbuf, as_buf, ad_buf);
    k_aggregate<4, 16, false><<<NN / 4, 256, 0, stream>>>(hbuf, as_buf, ad_buf, rowptr, perm, src, ew,
                                                          We1, ae1, b1, nullptr, nullptr, nullptr, nullptr, feat);
    // layer 2: fin=64, H=4, C=32 (F=128)
    k_transform<64, 128, 128, 128, 4, 32><<<NN / 2, 256, 0, stream>>>(feat, W2, as2, ad2, hbuf, as_buf, ad_buf);
    k_aggregate<4, 32, false><<<NN / 4, 256, 0, stream>>>(hbuf, as_buf, ad_buf, rowptr, perm, src, ew,
                                                          We2, ae2, b2, nullptr, nullptr, nullptr, nullptr, feat);
    // layer 3: fin=128, H=4, C=16 (F=64)
    k_transform<128, 64, 64, 64, 4, 16><<<NN / 4, 256, 0, stream>>>(feat, W3, as3, ad3, hbuf, as_buf, ad_buf);
    k_aggregate<4, 16, false><<<NN / 4, 256, 0, stream>>>(hbuf, as_buf, ad_buf, rowptr, perm, src, ew,
                                                          We3, ae3, b3, nullptr, nullptr, nullptr, nullptr, feat);
    // layer 4: fin=64, H=1, C=50 (F=50, padded stride 64), fused bias+BN+lrelu, per-node out
    k_transform<64, 50, 64, 64, 1, 50><<<NN / 4, 256, 0, stream>>>(feat, W4, as4, ad4, hbuf, as_buf, ad_buf);
    k_aggregate<1, 50, true><<<NN / 4, 256, 0, stream>>>(hbuf, as_buf, ad_buf, rowptr, perm, src, ew,
                                                         We4, ae4, b4, bn_g, bn_b, bn_rm, bn_rv, feat);
    // graph pooling (sorted batch, binary search) + final MLP
    k_pool<<<NG / 4, 256, 0, stream>>>(feat, batch, gbuf);
    k_mlp<<<NG / 256, 256, 0, stream>>>(gbuf, Wf1, bf1, Wf2, bf2, Wf3, bf3, out);
}

// Round 5
// 1543.285 us; speedup vs baseline: 1.0549x; 1.0549x over previous
//
#include <hip/hip_runtime.h>
#include <hip/hip_fp16.h>
#include <math.h>

#define NN 131072
#define NE 2097152
#define NG 16384

__device__ __forceinline__ float lrelu(float x, float s) { return x > 0.f ? x : s * x; }

template <int H>
__device__ __forceinline__ float sel_h(const float* a, int hsel) {
    if constexpr (H == 1) return a[0];
    else return hsel == 0 ? a[0] : hsel == 1 ? a[1] : hsel == 2 ? a[2] : a[3];
}

// ---------------- CSR build ----------------
__global__ void k_hist(const int* __restrict__ dst, int* __restrict__ cnt) {
    int e = blockIdx.x * 256 + threadIdx.x;
    if (e < NE) atomicAdd(&cnt[dst[e]], 1);
}

__global__ void k_scan1(const int* __restrict__ cnt, int* __restrict__ rowptr, int* __restrict__ part) {
    __shared__ int s[256];
    int t = threadIdx.x;
    int i = blockIdx.x * 256 + t;
    int v = cnt[i];
    s[t] = v;
    __syncthreads();
    for (int off = 1; off < 256; off <<= 1) {
        int x = (t >= off) ? s[t - off] : 0;
        __syncthreads();
        s[t] += x;
        __syncthreads();
    }
    rowptr[i] = s[t] - v;  // exclusive
    if (t == 255) part[blockIdx.x] = s[255];
}

__global__ void k_scan2(int* part) {
    __shared__ int s[512];
    int t = threadIdx.x;
    int v = part[t];
    s[t] = v;
    __syncthreads();
    for (int off = 1; off < 512; off <<= 1) {
        int x = (t >= off) ? s[t - off] : 0;
        __syncthreads();
        s[t] += x;
        __syncthreads();
    }
    part[t] = s[t] - v;  // exclusive
}

__global__ void k_scan3(int* __restrict__ rowptr, const int* __restrict__ part, int* __restrict__ cursor) {
    int t = threadIdx.x;
    int i = blockIdx.x * 256 + t;
    int v = rowptr[i] + part[blockIdx.x];
    rowptr[i] = v;
    cursor[i] = v;
    if (i == 0) rowptr[NN] = NE;
}

__global__ void k_scatter(const int* __restrict__ dst, int* __restrict__ cursor, int* __restrict__ perm) {
    int e = blockIdx.x * 256 + threadIdx.x;
    if (e < NE) {
        int p = atomicAdd(&cursor[dst[e]], 1);
        perm[p] = e;
    }
}

// ---------------- node transform + fused alpha projections ----------------
template <int FIN, int F, int FP, int FSO, int H, int C>
__global__ void k_transform(const float* __restrict__ in, const float* __restrict__ W,
                            const float* __restrict__ as_, const float* __restrict__ ad_,
                            __half* __restrict__ h, float* __restrict__ alpha_s,
                            float* __restrict__ alpha_d) {
    constexpr int BN = 256 / FP;
    constexpr int GRP = ((C & (C - 1)) == 0) ? C : 64;
    __shared__ float Wl[FIN * F];
    __shared__ float xl[BN * FIN];
    int t = threadIdx.x;
    for (int i = t; i < FIN * F; i += 256) Wl[i] = W[i];
    int nb = blockIdx.x * BN;
    for (int i = t; i < BN * FIN; i += 256) xl[i] = in[(size_t)nb * FIN + i];
    __syncthreads();
    int nl = t / FP, f = t % FP;
    int n = nb + nl;
    float acc = 0.f;
    if (f < F) {
#pragma unroll
        for (int k = 0; k < FIN; k++) acc += xl[nl * FIN + k] * Wl[k * F + f];
        h[(size_t)n * FSO + f] = __float2half(acc);
    } else if (f < FSO) {
        h[(size_t)n * FSO + f] = __float2half(0.f);
    }
    float hs = (f < F) ? acc * as_[f] : 0.f;
    float hd = (f < F) ? acc * ad_[f] : 0.f;
#pragma unroll
    for (int off = 1; off < GRP; off <<= 1) {
        hs += __shfl_xor(hs, off);
        hd += __shfl_xor(hd, off);
    }
    if ((f % GRP) == 0 && f < F) {
        alpha_s[(size_t)n * H + f / GRP] = hs;
        alpha_d[(size_t)n * H + f / GRP] = hd;
    }
}

// ---------------- per-node softmax + aggregation (1 wave / node, 4 nodes / block) ----------------
// No max-pass (alpha O(1), clamped at 80). Phase 2: EPI edges/iter, uint2
// 4-feature gathers, src+att staged in LDS, unroll 4 for memory-level parallelism.
template <int H, int C, bool FINAL>
__global__ __launch_bounds__(256) void k_aggregate(
    const __half* __restrict__ h, const float* __restrict__ asrc, const float* __restrict__ adst,
    const int* __restrict__ rowptr, const int* __restrict__ perm,
    const int* __restrict__ srcs, const float* __restrict__ ew,
    const float* __restrict__ We, const float* __restrict__ ae, const float* __restrict__ b,
    const float* __restrict__ bn_g, const float* __restrict__ bn_b,
    const float* __restrict__ bn_rm, const float* __restrict__ bn_rv,
    float* __restrict__ out) {
    constexpr int F = H * C;
    constexpr bool P2 = (F > 64);
    constexpr int FS = P2 ? 128 : 64;  // h row stride in halves
    constexpr int LPE = P2 ? 32 : 16;  // lanes per edge
    constexpr int EPI = 64 / LPE;      // edges per iteration (2 or 4)
    __shared__ float lds_att[4][(64 + EPI) * H];
    __shared__ int lds_s[4][64 + EPI];

    int wid = threadIdx.x >> 6;
    int lane = threadIdx.x & 63;
    int n = blockIdx.x * 4 + wid;
    int r0 = __builtin_amdgcn_readfirstlane(rowptr[n]);
    int r1 = __builtin_amdgcn_readfirstlane(rowptr[n + 1]);
    int deg = r1 - r0;

    // per-head constants
    float ce[H], ad[H];
#pragma unroll
    for (int hh = 0; hh < H; hh++) {
        float c = 0.f;
#pragma unroll
        for (int cc = 0; cc < C; cc++) c += We[hh * C + cc] * ae[hh * C + cc];
        ce[hh] = c;
    }
    if constexpr (H == 4) {
        float4 adv = ((const float4*)adst)[n];
        ad[0] = adv.x; ad[1] = adv.y; ad[2] = adv.z; ad[3] = adv.w;
    } else {
        ad[0] = adst[n];
    }

    // ---- phase 1: one edge per lane; exp(alpha) directly ----
    bool val = lane < deg;
    int s_l = 0;
    float w_l = 0.f;
    if (val) {
        int e = perm[r0 + lane];
        s_l = srcs[e];
        w_l = ew[e];
    }
    float ex_l[H], psum[H];
    if constexpr (H == 4) {
        if (val) {
            float4 v4 = ((const float4*)asrc)[s_l];
            ex_l[0] = __expf(fminf(lrelu(v4.x + ad[0] + w_l * ce[0], 0.2f), 80.f));
            ex_l[1] = __expf(fminf(lrelu(v4.y + ad[1] + w_l * ce[1], 0.2f), 80.f));
            ex_l[2] = __expf(fminf(lrelu(v4.z + ad[2] + w_l * ce[2], 0.2f), 80.f));
            ex_l[3] = __expf(fminf(lrelu(v4.w + ad[3] + w_l * ce[3], 0.2f), 80.f));
        } else {
            ex_l[0] = ex_l[1] = ex_l[2] = ex_l[3] = 0.f;
        }
    } else {
        ex_l[0] = val ? __expf(fminf(lrelu(asrc[s_l] + ad[0] + w_l * ce[0], 0.2f), 80.f)) : 0.f;
    }
#pragma unroll
    for (int hh = 0; hh < H; hh++) psum[hh] = ex_l[hh];
    // overflow edges (deg > 64, rare): add into denom
    for (int r = r0 + 64 + lane; r < r1; r += 64) {
        int e = perm[r];
        int s = srcs[e];
        float w = ew[e];
        if constexpr (H == 4) {
            float4 v4 = ((const float4*)asrc)[s];
            psum[0] += __expf(fminf(lrelu(v4.x + ad[0] + w * ce[0], 0.2f), 80.f));
            psum[1] += __expf(fminf(lrelu(v4.y + ad[1] + w * ce[1], 0.2f), 80.f));
            psum[2] += __expf(fminf(lrelu(v4.z + ad[2] + w * ce[2], 0.2f), 80.f));
            psum[3] += __expf(fminf(lrelu(v4.w + ad[3] + w * ce[3], 0.2f), 80.f));
        } else {
            psum[0] += __expf(fminf(lrelu(asrc[s] + ad[0] + w * ce[0], 0.2f), 80.f));
        }
    }
    float rden[H];
#pragma unroll
    for (int hh = 0; hh < H; hh++) {
        float v = psum[hh];
#pragma unroll
        for (int off = 32; off >= 1; off >>= 1) v += __shfl_xor(v, off);
        rden[hh] = 1.f / (v + 1e-16f);
    }

    // stage att = ex/den and src in LDS (+ zero pad for unroll overrun)
    lds_s[wid][lane] = s_l;
#pragma unroll
    for (int hh = 0; hh < H; hh++) lds_att[wid][lane * H + hh] = ex_l[hh] * rden[hh];
    if (lane < EPI) lds_s[wid][64 + lane] = 0;
    if (lane < EPI * H) lds_att[wid][64 * H + lane] = 0.f;
    __syncthreads();

    // ---- phase 2: EPI edges per iter, 4 features (uint2) per lane, unroll 4 ----
    int jn = deg < 64 ? deg : 64;
    int flane = lane & (LPE - 1);
    int grp = lane / LPE;
    int f0 = 4 * flane;
    int hsel = (H == 1) ? 0 : (f0 / C);
    const uint2* h2 = (const uint2*)h;
    float a0 = 0.f, a1 = 0.f, a2 = 0.f, a3 = 0.f;
#pragma unroll 4
    for (int j = 0; j < jn; j += EPI) {
        int je = j + grp;
        int s = lds_s[wid][je];
        float att = lds_att[wid][je * H + hsel];
        uint2 p = h2[(size_t)s * (FS / 4) + flane];
        __half2 p01 = *(__half2*)&p.x;
        __half2 p23 = *(__half2*)&p.y;
        a0 = fmaf(__low2float(p01), att, a0);
        a1 = fmaf(__high2float(p01), att, a1);
        a2 = fmaf(__low2float(p23), att, a2);
        a3 = fmaf(__high2float(p23), att, a3);
    }
    if (deg > 64) {  // rare
        float rdensel = sel_h<H>(rden, hsel);
        for (int r = r0 + 64; r < r1; ++r) {
            int e = __builtin_amdgcn_readfirstlane(perm[r]);
            int s = __builtin_amdgcn_readfirstlane(srcs[e]);
            float w = ew[e];
            float aA[H];
            if constexpr (H == 4) {
                float4 v4 = ((const float4*)asrc)[s];
                aA[0] = fminf(lrelu(v4.x + ad[0] + w * ce[0], 0.2f), 80.f);
                aA[1] = fminf(lrelu(v4.y + ad[1] + w * ce[1], 0.2f), 80.f);
                aA[2] = fminf(lrelu(v4.z + ad[2] + w * ce[2], 0.2f), 80.f);
                aA[3] = fminf(lrelu(v4.w + ad[3] + w * ce[3], 0.2f), 80.f);
            } else {
                aA[0] = fminf(lrelu(asrc[s] + ad[0] + w * ce[0], 0.2f), 80.f);
            }
            float att = __expf(sel_h<H>(aA, hsel)) * rdensel;
            att = (grp == 0) ? att : 0.f;
            uint2 p = h2[(size_t)s * (FS / 4) + flane];
            __half2 p01 = *(__half2*)&p.x;
            __half2 p23 = *(__half2*)&p.y;
            a0 = fmaf(__low2float(p01), att, a0);
            a1 = fmaf(__high2float(p01), att, a1);
            a2 = fmaf(__low2float(p23), att, a2);
            a3 = fmaf(__high2float(p23), att, a3);
        }
    }

    // combine across edge groups
    a0 += __shfl_xor(a0, 32);
    a1 += __shfl_xor(a1, 32);
    a2 += __shfl_xor(a2, 32);
    a3 += __shfl_xor(a3, 32);
    if constexpr (!P2) {
        a0 += __shfl_xor(a0, 16);
        a1 += __shfl_xor(a1, 16);
        a2 += __shfl_xor(a2, 16);
        a3 += __shfl_xor(a3, 16);
    }

    if constexpr (P2) {
        if (lane < 32) {
            float4 o;
            o.x = lrelu(a0 + b[f0], 0.01f);
            o.y = lrelu(a1 + b[f0 + 1], 0.01f);
            o.z = lrelu(a2 + b[f0 + 2], 0.01f);
            o.w = lrelu(a3 + b[f0 + 3], 0.01f);
            ((float4*)out)[(size_t)n * 32 + lane] = o;
        }
    } else if constexpr (FINAL) {
        if (lane < 16 && f0 < 50) {
            float o[4] = {a0, a1, a2, a3};
#pragma unroll
            for (int k = 0; k < 4; k++) {
                int f = f0 + k;
                if (f < 50) {
                    float v = o[k] + b[f];
                    v = (v - bn_rm[f]) * rsqrtf(bn_rv[f] + 1e-5f) * bn_g[f] + bn_b[f];
                    o[k] = lrelu(v, 0.01f);
                }
            }
            if (f0 < 48) {
                ((float4*)(out + (size_t)n * 64 + f0))[0] = make_float4(o[0], o[1], o[2], o[3]);
            } else {
                ((float2*)(out + (size_t)n * 64 + 48))[0] = make_float2(o[0], o[1]);
            }
        }
    } else {
        if (lane < 16) {
            float4 o;
            o.x = lrelu(a0 + b[f0], 0.01f);
            o.y = lrelu(a1 + b[f0 + 1], 0.01f);
            o.z = lrelu(a2 + b[f0 + 2], 0.01f);
            o.w = lrelu(a3 + b[f0 + 3], 0.01f);
            ((float4*)out)[(size_t)n * 16 + lane] = o;
        }
    }
}

// ---------------- graph pooling: segment-sum via sorted batch (binary search) ----------------
__global__ __launch_bounds__(256) void k_pool(const float* __restrict__ nodeout, const int* __restrict__ batch,
                                              float* __restrict__ gbuf) {
    int wid = threadIdx.x >> 6;
    int lane = threadIdx.x & 63;
    int g = blockIdx.x * 4 + wid;
    int lo = 0, hi = NN;
    while (lo < hi) {
        int mid = (lo + hi) >> 1;
        if (batch[mid] < g) lo = mid + 1; else hi = mid;
    }
    int s0 = lo;
    hi = NN;
    while (lo < hi) {
        int mid = (lo + hi) >> 1;
        if (batch[mid] < g + 1) lo = mid + 1; else hi = mid;
    }
    int s1 = lo;
    if (lane < 50) {
        float acc = 0.f;
        for (int n = s0; n < s1; ++n) acc += nodeout[(size_t)n * 64 + lane];
        gbuf[(size_t)g * 50 + lane] = acc;
    }
}

// ---------------- final MLP over graphs ----------------
__global__ void k_mlp(const float* __restrict__ gbuf,
                      const float* __restrict__ Wf1, const float* __restrict__ bf1,
                      const float* __restrict__ Wf2, const float* __restrict__ bf2,
                      const float* __restrict__ Wf3, const float* __restrict__ bf3,
                      float* __restrict__ out) {
    __shared__ float W1[1500], W2[600], W3[40], B1[30], B2[20], B3[2];
    int t = threadIdx.x;
    for (int i = t; i < 1500; i += 256) W1[i] = Wf1[i];
    for (int i = t; i < 600; i += 256) W2[i] = Wf2[i];
    for (int i = t; i < 40; i += 256) W3[i] = Wf3[i];
    if (t < 30) B1[t] = bf1[t];
    if (t < 20) B2[t] = bf2[t];
    if (t < 2) B3[t] = bf3[t];
    __syncthreads();
    int g = blockIdx.x * 256 + t;
    float gv[50];
#pragma unroll
    for (int i = 0; i < 50; i++) gv[i] = gbuf[(size_t)g * 50 + i];
    float h1[30];
#pragma unroll
    for (int j = 0; j < 30; j++) {
        float a = B1[j];
#pragma unroll
        for (int i = 0; i < 50; i++) a += gv[i] * W1[i * 30 + j];
        h1[j] = lrelu(a, 0.01f);
    }
    float h2[20];
#pragma unroll
    for (int j = 0; j < 20; j++) {
        float a = B2[j];
#pragma unroll
        for (int i = 0; i < 30; i++) a += h1[i] * W2[i * 20 + j];
        h2[j] = lrelu(a, 0.01f);
    }
#pragma unroll
    for (int j = 0; j < 2; j++) {
        float a = B3[j];
#pragma unroll
        for (int i = 0; i < 20; i++) a += h2[i] * W3[i * 2 + j];
        out[(size_t)g * 2 + j] = a;
    }
}

extern "C" void kernel_launch(void* const* d_in, const int* in_sizes, int n_in,
                              void* d_out, int out_size, void* d_ws, size_t ws_size,
                              hipStream_t stream) {
    const float* x = (const float*)d_in[0];
    const int* ei = (const int*)d_in[1];
    const float* ew = (const float*)d_in[2];
    const int* batch = (const int*)d_in[3];
    const float* W1 = (const float*)d_in[4];
    const float* as1 = (const float*)d_in[5];
    const float* ad1 = (const float*)d_in[6];
    const float* We1 = (const float*)d_in[7];
    const float* ae1 = (const float*)d_in[8];
    const float* b1 = (const float*)d_in[9];
    const float* W2 = (const float*)d_in[10];
    const float* as2 = (const float*)d_in[11];
    const float* ad2 = (const float*)d_in[12];
    const float* We2 = (const float*)d_in[13];
    const float* ae2 = (const float*)d_in[14];
    const float* b2 = (const float*)d_in[15];
    const float* W3 = (const float*)d_in[16];
    const float* as3 = (const float*)d_in[17];
    const float* ad3 = (const float*)d_in[18];
    const float* We3 = (const float*)d_in[19];
    const float* ae3 = (const float*)d_in[20];
    const float* b3 = (const float*)d_in[21];
    const float* W4 = (const float*)d_in[22];
    const float* as4 = (const float*)d_in[23];
    const float* ad4 = (const float*)d_in[24];
    const float* We4 = (const float*)d_in[25];
    const float* ae4 = (const float*)d_in[26];
    const float* b4 = (const float*)d_in[27];
    const float* bn_g = (const float*)d_in[28];
    const float* bn_b = (const float*)d_in[29];
    const float* bn_rm = (const float*)d_in[30];
    const float* bn_rv = (const float*)d_in[31];
    const float* Wf1 = (const float*)d_in[32];
    const float* bf1 = (const float*)d_in[33];
    const float* Wf2 = (const float*)d_in[34];
    const float* bf2 = (const float*)d_in[35];
    const float* Wf3 = (const float*)d_in[36];
    const float* bf3 = (const float*)d_in[37];
    float* out = (float*)d_out;

    const int* src = ei;
    const int* dst = ei + NE;

    // workspace layout
    char* ws = (char*)d_ws;
    float* feat = (float*)ws;   ws += (size_t)NN * 128 * 4;  // 64 MB
    __half* hbuf = (__half*)ws; ws += (size_t)NN * 128 * 2;  // 32 MB
    float* as_buf = (float*)ws; ws += (size_t)NN * 4 * 4;
    float* ad_buf = (float*)ws; ws += (size_t)NN * 4 * 4;
    int* cnt = (int*)ws;        ws += (size_t)NN * 4;
    int* rowptr = (int*)ws;     ws += (size_t)(NN + 64) * 4;
    int* cursor = (int*)ws;     ws += (size_t)NN * 4;
    int* perm = (int*)ws;       ws += (size_t)NE * 4;
    int* part = (int*)ws;       ws += 512 * 4;
    float* gbuf = (float*)ws;   ws += (size_t)NG * 50 * 4;

    // CSR build
    hipMemsetAsync(cnt, 0, (size_t)NN * 4, stream);
    k_hist<<<NE / 256, 256, 0, stream>>>(dst, cnt);
    k_scan1<<<NN / 256, 256, 0, stream>>>(cnt, rowptr, part);
    k_scan2<<<1, 512, 0, stream>>>(part);
    k_scan3<<<NN / 256, 256, 0, stream>>>(rowptr, part, cursor);
    k_scatter<<<NE / 256, 256, 0, stream>>>(dst, cursor, perm);

    // layer 1: fin=6, H=4, C=16 (F=64)
    k_transform<6, 64, 64, 64, 4, 16><<<NN / 4, 256, 0, stream>>>(x, W1, as1, ad1, hbuf, as_buf, ad_buf);
    k_aggregate<4, 16, false><<<NN / 4, 256, 0, stream>>>(hbuf, as_buf, ad_buf, rowptr, perm, src, ew,
                                                          We1, ae1, b1, nullptr, nullptr, nullptr, nullptr, feat);
    // layer 2: fin=64, H=4, C=32 (F=128)
    k_transform<64, 128, 128, 128, 4, 32><<<NN / 2, 256, 0, stream>>>(feat, W2, as2, ad2, hbuf, as_buf, ad_buf);
    k_aggregate<4, 32, false><<<NN / 4, 256, 0, stream>>>(hbuf, as_buf, ad_buf, rowptr, perm, src, ew,
                                                          We2, ae2, b2, nullptr, nullptr, nullptr, nullptr, feat);
    // layer 3: fin=128, H=4, C=16 (F=64)
    k_transform<128, 64, 64, 64, 4, 16><<<NN / 4, 256, 0, stream>>>(feat, W3, as3, ad3, hbuf, as_buf, ad_buf);
    k_aggregate<4, 16, false><<<NN / 4, 256, 0, stream>>>(hbuf, as_buf, ad_buf, rowptr, perm, src, ew,
                                                          We3, ae3, b3, nullptr, nullptr, nullptr, nullptr, feat);
    // layer 4: fin=64, H=1, C=50 (F=50, padded stride 64), fused bias+BN+lrelu, per-node out
    k_transform<64, 50, 64, 64, 1, 50><<<NN / 4, 256, 0, stream>>>(feat, W4, as4, ad4, hbuf, as_buf, ad_buf);
    k_aggregate<1, 50, true><<<NN / 4, 256, 0, stream>>>(hbuf, as_buf, ad_buf, rowptr, perm, src, ew,
                                                         We4, ae4, b4, bn_g, bn_b, bn_rm, bn_rv, feat);
    // graph pooling (sorted batch, binary search) + final MLP
    k_pool<<<NG / 4, 256, 0, stream>>>(feat, batch, gbuf);
    k_mlp<<<NG / 256, 256, 0, stream>>>(gbuf, Wf1, bf1, Wf2, bf2, Wf3, bf3, out);
}

// Round 6
// 1233.870 us; speedup vs baseline: 1.3195x; 1.2508x over previous
//
#include <hip/hip_runtime.h>
#include <hip/hip_fp16.h>
#include <math.h>

#define NN 131072
#define NE 2097152
#define NG 16384

__device__ __forceinline__ float lrelu(float x, float s) { return fmaxf(x, s * x); }

template <int H>
__device__ __forceinline__ float sel_h(const float* a, int hsel) {
    if constexpr (H == 1) return a[0];
    else return hsel == 0 ? a[0] : hsel == 1 ? a[1] : hsel == 2 ? a[2] : a[3];
}

// ---------------- CSR build ----------------
__global__ void k_hist(const int* __restrict__ dst, int* __restrict__ cnt) {
    int e = blockIdx.x * 256 + threadIdx.x;
    if (e < NE) atomicAdd(&cnt[dst[e]], 1);
}

__global__ void k_scan1(const int* __restrict__ cnt, int* __restrict__ rowptr, int* __restrict__ part) {
    __shared__ int s[256];
    int t = threadIdx.x;
    int i = blockIdx.x * 256 + t;
    int v = cnt[i];
    s[t] = v;
    __syncthreads();
    for (int off = 1; off < 256; off <<= 1) {
        int x = (t >= off) ? s[t - off] : 0;
        __syncthreads();
        s[t] += x;
        __syncthreads();
    }
    rowptr[i] = s[t] - v;  // exclusive
    if (t == 255) part[blockIdx.x] = s[255];
}

// scan of block partials + per-layer attention-edge constants ce[h] = dot(We[h], ae[h])
__global__ void k_scan2(int* part,
                        const float* __restrict__ We1, const float* __restrict__ ae1,
                        const float* __restrict__ We2, const float* __restrict__ ae2,
                        const float* __restrict__ We3, const float* __restrict__ ae3,
                        const float* __restrict__ We4, const float* __restrict__ ae4,
                        float* __restrict__ ceb) {
    __shared__ int s[512];
    int t = threadIdx.x;
    int v = part[t];
    s[t] = v;
    __syncthreads();
    for (int off = 1; off < 512; off <<= 1) {
        int x = (t >= off) ? s[t - off] : 0;
        __syncthreads();
        s[t] += x;
        __syncthreads();
    }
    part[t] = s[t] - v;  // exclusive
    if (t < 4) {
        float c = 0.f;
        for (int i = 0; i < 16; i++) c += We1[t * 16 + i] * ae1[t * 16 + i];
        ceb[t] = c;
    } else if (t < 8) {
        int h = t - 4;
        float c = 0.f;
        for (int i = 0; i < 32; i++) c += We2[h * 32 + i] * ae2[h * 32 + i];
        ceb[t] = c;
    } else if (t < 12) {
        int h = t - 8;
        float c = 0.f;
        for (int i = 0; i < 16; i++) c += We3[h * 16 + i] * ae3[h * 16 + i];
        ceb[t] = c;
    } else if (t == 12) {
        float c = 0.f;
        for (int i = 0; i < 50; i++) c += We4[i] * ae4[i];
        ceb[t] = c;
    }
}

__global__ void k_scan3(int* __restrict__ rowptr, const int* __restrict__ part, int* __restrict__ cursor) {
    int t = threadIdx.x;
    int i = blockIdx.x * 256 + t;
    int v = rowptr[i] + part[blockIdx.x];
    rowptr[i] = v;
    cursor[i] = v;
    if (i == 0) rowptr[NN] = NE;
}

// scatter edges into dst-sorted order, packing (src, ew) into one uint:
// u = (src << 15) | round(ew * 32767)   (ew in [0,1); alpha err ~5e-5, negligible)
__global__ void k_scatter(const int* __restrict__ src, const int* __restrict__ dst,
                          const float* __restrict__ ew, int* __restrict__ cursor,
                          unsigned int* __restrict__ ep) {
    int e = blockIdx.x * 256 + threadIdx.x;
    if (e < NE) {
        int p = atomicAdd(&cursor[dst[e]], 1);
        unsigned int s = (unsigned int)src[e];
        unsigned int q = (unsigned int)(ew[e] * 32767.f + 0.5f);
        ep[p] = (s << 15) | (q & 0x7fffu);
    }
}

__device__ __forceinline__ void ep_unpack(unsigned int u, int& s, float& w) {
    s = (int)(u >> 15);
    w = (float)(u & 0x7fffu) * (1.f / 32767.f);
}

// ---------------- node transform + fused alpha projections ----------------
// h = in @ W (fp16, zero-padded to FSO); alpha_s/d via in-wave shuffle reduction.
// ITER node-chunks per block amortize the W-tile staging.
template <int FIN, int F, int FP, int FSO, int H, int C, int ITER>
__global__ void k_transform(const float* __restrict__ in, const float* __restrict__ W,
                            const float* __restrict__ as_, const float* __restrict__ ad_,
                            __half* __restrict__ h, float* __restrict__ alpha_s,
                            float* __restrict__ alpha_d) {
    constexpr int BN = 256 / FP;
    constexpr int GRP = ((C & (C - 1)) == 0) ? C : 64;
    __shared__ float Wl[FIN * F];
    __shared__ float xl[BN * FIN];
    int t = threadIdx.x;
    for (int i = t; i < FIN * F; i += 256) Wl[i] = W[i];
    int nl = t / FP, f = t % FP;
    float asf = (f < F) ? as_[f] : 0.f;
    float adf = (f < F) ? ad_[f] : 0.f;
    for (int it = 0; it < ITER; ++it) {
        int nb = (blockIdx.x * ITER + it) * BN;
        __syncthreads();
        for (int i = t; i < BN * FIN; i += 256) xl[i] = in[(size_t)nb * FIN + i];
        __syncthreads();
        int n = nb + nl;
        float acc = 0.f;
        if (f < F) {
#pragma unroll
            for (int k = 0; k < FIN; k++) acc += xl[nl * FIN + k] * Wl[k * F + f];
            h[(size_t)n * FSO + f] = __float2half(acc);
        } else if (f < FSO) {
            h[(size_t)n * FSO + f] = __float2half(0.f);
        }
        float hs = acc * asf;
        float hd = acc * adf;
#pragma unroll
        for (int off = 1; off < GRP; off <<= 1) {
            hs += __shfl_xor(hs, off);
            hd += __shfl_xor(hd, off);
        }
        if ((f % GRP) == 0 && f < F) {
            alpha_s[(size_t)n * H + f / GRP] = hs;
            alpha_d[(size_t)n * H + f / GRP] = hd;
        }
    }
}

// ---------------- per-node softmax + aggregation (1 wave / node, 4 nodes / block) ----------------
// No max-pass (alpha O(1), clamped at 80). Phase 1: coalesced packed-edge loads.
// Phase 2: byte-offsets staged in LDS; F=128 uses uint4 (8 feat/lane, 4 edges/iter),
// F<=64 uses uint2 (4 feat/lane, 4 edges/iter); unroll 4 for MLP.
template <int H, int C, bool FINAL>
__global__ __launch_bounds__(256) void k_aggregate(
    const __half* __restrict__ h, const float* __restrict__ asrc, const float* __restrict__ adst,
    const int* __restrict__ rowptr, const unsigned int* __restrict__ ep,
    const float* __restrict__ ceb, const float* __restrict__ b,
    const float* __restrict__ bn_g, const float* __restrict__ bn_b,
    const float* __restrict__ bn_rm, const float* __restrict__ bn_rv,
    float* __restrict__ out) {
    constexpr int F = H * C;
    constexpr bool P2 = (F > 64);
    constexpr int FSB = P2 ? 256 : 128;  // h row stride in BYTES
    constexpr int EPI = 4;
    __shared__ float lds_att[4][(64 + EPI) * H];
    __shared__ int lds_off[4][64 + EPI];

    int wid = threadIdx.x >> 6;
    int lane = threadIdx.x & 63;
    int n = blockIdx.x * 4 + wid;
    int r0 = __builtin_amdgcn_readfirstlane(rowptr[n]);
    int r1 = __builtin_amdgcn_readfirstlane(rowptr[n + 1]);
    int deg = r1 - r0;

    // per-head constants (uniform scalar loads)
    float ce[H], ad[H];
#pragma unroll
    for (int hh = 0; hh < H; hh++) ce[hh] = ceb[hh];
    if constexpr (H == 4) {
        float4 adv = ((const float4*)adst)[n];
        ad[0] = adv.x; ad[1] = adv.y; ad[2] = adv.z; ad[3] = adv.w;
    } else {
        ad[0] = adst[n];
    }

    // ---- phase 1: one edge per lane; exp(alpha) directly ----
    bool val = lane < deg;
    int s_l = 0;
    float w_l = 0.f;
    if (val) ep_unpack(ep[r0 + lane], s_l, w_l);
    float ex_l[H], psum[H];
    if constexpr (H == 4) {
        if (val) {
            float4 v4 = ((const float4*)asrc)[s_l];
            ex_l[0] = __expf(fminf(lrelu(v4.x + ad[0] + w_l * ce[0], 0.2f), 80.f));
            ex_l[1] = __expf(fminf(lrelu(v4.y + ad[1] + w_l * ce[1], 0.2f), 80.f));
            ex_l[2] = __expf(fminf(lrelu(v4.z + ad[2] + w_l * ce[2], 0.2f), 80.f));
            ex_l[3] = __expf(fminf(lrelu(v4.w + ad[3] + w_l * ce[3], 0.2f), 80.f));
        } else {
            ex_l[0] = ex_l[1] = ex_l[2] = ex_l[3] = 0.f;
        }
    } else {
        ex_l[0] = val ? __expf(fminf(lrelu(asrc[s_l] + ad[0] + w_l * ce[0], 0.2f), 80.f)) : 0.f;
    }
#pragma unroll
    for (int hh = 0; hh < H; hh++) psum[hh] = ex_l[hh];
    // overflow edges (deg > 64, rare): add into denom
    for (int r = r0 + 64 + lane; r < r1; r += 64) {
        int s;
        float w;
        ep_unpack(ep[r], s, w);
        if constexpr (H == 4) {
            float4 v4 = ((const float4*)asrc)[s];
            psum[0] += __expf(fminf(lrelu(v4.x + ad[0] + w * ce[0], 0.2f), 80.f));
            psum[1] += __expf(fminf(lrelu(v4.y + ad[1] + w * ce[1], 0.2f), 80.f));
            psum[2] += __expf(fminf(lrelu(v4.z + ad[2] + w * ce[2], 0.2f), 80.f));
            psum[3] += __expf(fminf(lrelu(v4.w + ad[3] + w * ce[3], 0.2f), 80.f));
        } else {
            psum[0] += __expf(fminf(lrelu(asrc[s] + ad[0] + w * ce[0], 0.2f), 80.f));
        }
    }
    float rden[H];
#pragma unroll
    for (int hh = 0; hh < H; hh++) {
        float v = psum[hh];
#pragma unroll
        for (int off = 32; off >= 1; off >>= 1) v += __shfl_xor(v, off);
        rden[hh] = 1.f / (v + 1e-16f);
    }

    // stage att = ex/den and row byte-offset in LDS (+ zero pad for unroll overrun)
    lds_off[wid][lane] = s_l * FSB;
#pragma unroll
    for (int hh = 0; hh < H; hh++) lds_att[wid][lane * H + hh] = ex_l[hh] * rden[hh];
    if (lane < EPI) lds_off[wid][64 + lane] = 0;
    if (lane < EPI * H) lds_att[wid][64 * H + lane] = 0.f;
    __syncthreads();

    int jn = deg < 64 ? deg : 64;
    int flane = lane & 15;
    int grp = lane >> 4;
    const char* hb = (const char*)h;

    if constexpr (P2) {
        // F=128: 16 lanes/edge, 8 features (uint4) per lane, 4 edges/iter
        int f0 = 8 * flane;
        int hsel = f0 >> 5;  // C=32
        float a[8];
#pragma unroll
        for (int i = 0; i < 8; i++) a[i] = 0.f;
#pragma unroll 4
        for (int j = 0; j < jn; j += EPI) {
            int je = j + grp;
            int off = lds_off[wid][je];
            float att = lds_att[wid][je * H + hsel];
            uint4 p = *(const uint4*)(hb + (size_t)(off + flane * 16));
            const __half2* hp = (const __half2*)&p;
#pragma unroll
            for (int i = 0; i < 4; i++) {
                a[2 * i] = fmaf(__low2float(hp[i]), att, a[2 * i]);
                a[2 * i + 1] = fmaf(__high2float(hp[i]), att, a[2 * i + 1]);
            }
        }
        if (deg > 64) {  // rare
            float rdensel = sel_h<H>(rden, hsel);
            for (int r = r0 + 64; r < r1; ++r) {
                unsigned int u = __builtin_amdgcn_readfirstlane(ep[r]);
                int s;
                float w;
                ep_unpack(u, s, w);
                float4 v4 = ((const float4*)asrc)[s];
                float aA[4];
                aA[0] = fminf(lrelu(v4.x + ad[0] + w * ce[0], 0.2f), 80.f);
                aA[1] = fminf(lrelu(v4.y + ad[1] + w * ce[1], 0.2f), 80.f);
                aA[2] = fminf(lrelu(v4.z + ad[2] + w * ce[2], 0.2f), 80.f);
                aA[3] = fminf(lrelu(v4.w + ad[3] + w * ce[3], 0.2f), 80.f);
                float att = __expf(sel_h<H>(aA, hsel)) * rdensel;
                att = (grp == 0) ? att : 0.f;
                uint4 p = *(const uint4*)(hb + (size_t)(s * FSB + flane * 16));
                const __half2* hp = (const __half2*)&p;
#pragma unroll
                for (int i = 0; i < 4; i++) {
                    a[2 * i] = fmaf(__low2float(hp[i]), att, a[2 * i]);
                    a[2 * i + 1] = fmaf(__high2float(hp[i]), att, a[2 * i + 1]);
                }
            }
        }
#pragma unroll
        for (int i = 0; i < 8; i++) {
            a[i] += __shfl_xor(a[i], 32);
            a[i] += __shfl_xor(a[i], 16);
        }
        if (lane < 16) {
            float4 o0, o1;
            o0.x = lrelu(a[0] + b[f0], 0.01f);
            o0.y = lrelu(a[1] + b[f0 + 1], 0.01f);
            o0.z = lrelu(a[2] + b[f0 + 2], 0.01f);
            o0.w = lrelu(a[3] + b[f0 + 3], 0.01f);
            o1.x = lrelu(a[4] + b[f0 + 4], 0.01f);
            o1.y = lrelu(a[5] + b[f0 + 5], 0.01f);
            o1.z = lrelu(a[6] + b[f0 + 6], 0.01f);
            o1.w = lrelu(a[7] + b[f0 + 7], 0.01f);
            ((float4*)out)[(size_t)n * 32 + 2 * flane] = o0;
            ((float4*)out)[(size_t)n * 32 + 2 * flane + 1] = o1;
        }
    } else {
        // F<=64: 16 lanes/edge, 4 features (uint2) per lane, 4 edges/iter
        int f0 = 4 * flane;
        int hsel = (H == 1) ? 0 : (f0 >> 4);  // C=16
        float a0 = 0.f, a1 = 0.f, a2 = 0.f, a3 = 0.f;
#pragma unroll 4
        for (int j = 0; j < jn; j += EPI) {
            int je = j + grp;
            int off = lds_off[wid][je];
            float att = lds_att[wid][je * H + hsel];
            uint2 p = *(const uint2*)(hb + (size_t)(off + flane * 8));
            __half2 p01 = *(__half2*)&p.x;
            __half2 p23 = *(__half2*)&p.y;
            a0 = fmaf(__low2float(p01), att, a0);
            a1 = fmaf(__high2float(p01), att, a1);
            a2 = fmaf(__low2float(p23), att, a2);
            a3 = fmaf(__high2float(p23), att, a3);
        }
        if (deg > 64) {  // rare
            float rdensel = sel_h<H>(rden, hsel);
            for (int r = r0 + 64; r < r1; ++r) {
                unsigned int u = __builtin_amdgcn_readfirstlane(ep[r]);
                int s;
                float w;
                ep_unpack(u, s, w);
                float aA[H];
                if constexpr (H == 4) {
                    float4 v4 = ((const float4*)asrc)[s];
                    aA[0] = fminf(lrelu(v4.x + ad[0] + w * ce[0], 0.2f), 80.f);
                    aA[1] = fminf(lrelu(v4.y + ad[1] + w * ce[1], 0.2f), 80.f);
                    aA[2] = fminf(lrelu(v4.z + ad[2] + w * ce[2], 0.2f), 80.f);
                    aA[3] = fminf(lrelu(v4.w + ad[3] + w * ce[3], 0.2f), 80.f);
                } else {
                    aA[0] = fminf(lrelu(asrc[s] + ad[0] + w * ce[0], 0.2f), 80.f);
                }
                float att = __expf(sel_h<H>(aA, hsel)) * rdensel;
                att = (grp == 0) ? att : 0.f;
                uint2 p = *(const uint2*)(hb + (size_t)(s * FSB + flane * 8));
                __half2 p01 = *(__half2*)&p.x;
                __half2 p23 = *(__half2*)&p.y;
                a0 = fmaf(__low2float(p01), att, a0);
                a1 = fmaf(__high2float(p01), att, a1);
                a2 = fmaf(__low2float(p23), att, a2);
                a3 = fmaf(__high2float(p23), att, a3);
            }
        }
        a0 += __shfl_xor(a0, 32);
        a1 += __shfl_xor(a1, 32);
        a2 += __shfl_xor(a2, 32);
        a3 += __shfl_xor(a3, 32);
        a0 += __shfl_xor(a0, 16);
        a1 += __shfl_xor(a1, 16);
        a2 += __shfl_xor(a2, 16);
        a3 += __shfl_xor(a3, 16);
        if constexpr (FINAL) {
            if (lane < 16 && f0 < 50) {
                float o[4] = {a0, a1, a2, a3};
#pragma unroll
                for (int k = 0; k < 4; k++) {
                    int f = f0 + k;
                    if (f < 50) {
                        float v = o[k] + b[f];
                        v = (v - bn_rm[f]) * rsqrtf(bn_rv[f] + 1e-5f) * bn_g[f] + bn_b[f];
                        o[k] = lrelu(v, 0.01f);
                    }
                }
                if (f0 < 48) {
                    ((float4*)(out + (size_t)n * 64 + f0))[0] = make_float4(o[0], o[1], o[2], o[3]);
                } else {
                    ((float2*)(out + (size_t)n * 64 + 48))[0] = make_float2(o[0], o[1]);
                }
            }
        } else {
            if (lane < 16) {
                float4 o;
                o.x = lrelu(a0 + b[f0], 0.01f);
                o.y = lrelu(a1 + b[f0 + 1], 0.01f);
                o.z = lrelu(a2 + b[f0 + 2], 0.01f);
                o.w = lrelu(a3 + b[f0 + 3], 0.01f);
                ((float4*)out)[(size_t)n * 16 + flane] = o;
            }
        }
    }
}

// ---------------- graph pooling: segment-sum via sorted batch (binary search) ----------------
__global__ __launch_bounds__(256) void k_pool(const float* __restrict__ nodeout, const int* __restrict__ batch,
                                              float* __restrict__ gbuf) {
    int wid = threadIdx.x >> 6;
    int lane = threadIdx.x & 63;
    int g = blockIdx.x * 4 + wid;
    int lo = 0, hi = NN;
    while (lo < hi) {
        int mid = (lo + hi) >> 1;
        if (batch[mid] < g) lo = mid + 1; else hi = mid;
    }
    int s0 = lo;
    hi = NN;
    while (lo < hi) {
        int mid = (lo + hi) >> 1;
        if (batch[mid] < g + 1) lo = mid + 1; else hi = mid;
    }
    int s1 = lo;
    if (lane < 50) {
        float acc = 0.f;
        for (int n = s0; n < s1; ++n) acc += nodeout[(size_t)n * 64 + lane];
        gbuf[(size_t)g * 50 + lane] = acc;
    }
}

// ---------------- final MLP over graphs ----------------
__global__ void k_mlp(const float* __restrict__ gbuf,
                      const float* __restrict__ Wf1, const float* __restrict__ bf1,
                      const float* __restrict__ Wf2, const float* __restrict__ bf2,
                      const float* __restrict__ Wf3, const float* __restrict__ bf3,
                      float* __restrict__ out) {
    __shared__ float W1[1500], W2[600], W3[40], B1[30], B2[20], B3[2];
    int t = threadIdx.x;
    for (int i = t; i < 1500; i += 256) W1[i] = Wf1[i];
    for (int i = t; i < 600; i += 256) W2[i] = Wf2[i];
    for (int i = t; i < 40; i += 256) W3[i] = Wf3[i];
    if (t < 30) B1[t] = bf1[t];
    if (t < 20) B2[t] = bf2[t];
    if (t < 2) B3[t] = bf3[t];
    __syncthreads();
    int g = blockIdx.x * 256 + t;
    float gv[50];
#pragma unroll
    for (int i = 0; i < 50; i++) gv[i] = gbuf[(size_t)g * 50 + i];
    float h1[30];
#pragma unroll
    for (int j = 0; j < 30; j++) {
        float a = B1[j];
#pragma unroll
        for (int i = 0; i < 50; i++) a += gv[i] * W1[i * 30 + j];
        h1[j] = lrelu(a, 0.01f);
    }
    float h2[20];
#pragma unroll
    for (int j = 0; j < 20; j++) {
        float a = B2[j];
#pragma unroll
        for (int i = 0; i < 30; i++) a += h1[i] * W2[i * 20 + j];
        h2[j] = lrelu(a, 0.01f);
    }
#pragma unroll
    for (int j = 0; j < 2; j++) {
        float a = B3[j];
#pragma unroll
        for (int i = 0; i < 20; i++) a += h2[i] * W3[i * 2 + j];
        out[(size_t)g * 2 + j] = a;
    }
}

extern "C" void kernel_launch(void* const* d_in, const int* in_sizes, int n_in,
                              void* d_out, int out_size, void* d_ws, size_t ws_size,
                              hipStream_t stream) {
    const float* x = (const float*)d_in[0];
    const int* ei = (const int*)d_in[1];
    const float* ew = (const float*)d_in[2];
    const int* batch = (const int*)d_in[3];
    const float* W1 = (const float*)d_in[4];
    const float* as1 = (const float*)d_in[5];
    const float* ad1 = (const float*)d_in[6];
    const float* We1 = (const float*)d_in[7];
    const float* ae1 = (const float*)d_in[8];
    const float* b1 = (const float*)d_in[9];
    const float* W2 = (const float*)d_in[10];
    const float* as2 = (const float*)d_in[11];
    const float* ad2 = (const float*)d_in[12];
    const float* We2 = (const float*)d_in[13];
    const float* ae2 = (const float*)d_in[14];
    const float* b2 = (const float*)d_in[15];
    const float* W3 = (const float*)d_in[16];
    const float* as3 = (const float*)d_in[17];
    const float* ad3 = (const float*)d_in[18];
    const float* We3 = (const float*)d_in[19];
    const float* ae3 = (const float*)d_in[20];
    const float* b3 = (const float*)d_in[21];
    const float* W4 = (const float*)d_in[22];
    const float* as4 = (const float*)d_in[23];
    const float* ad4 = (const float*)d_in[24];
    const float* We4 = (const float*)d_in[25];
    const float* ae4 = (const float*)d_in[26];
    const float* b4 = (const float*)d_in[27];
    const float* bn_g = (const float*)d_in[28];
    const float* bn_b = (const float*)d_in[29];
    const float* bn_rm = (const float*)d_in[30];
    const float* bn_rv = (const float*)d_in[31];
    const float* Wf1 = (const float*)d_in[32];
    const float* bf1 = (const float*)d_in[33];
    const float* Wf2 = (const float*)d_in[34];
    const float* bf2 = (const float*)d_in[35];
    const float* Wf3 = (const float*)d_in[36];
    const float* bf3 = (const float*)d_in[37];
    float* out = (float*)d_out;

    const int* src = ei;
    const int* dst = ei + NE;

    // workspace layout
    char* ws = (char*)d_ws;
    float* feat = (float*)ws;         ws += (size_t)NN * 128 * 4;  // 64 MB
    __half* hbuf = (__half*)ws;       ws += (size_t)NN * 128 * 2;  // 32 MB
    float* as_buf = (float*)ws;       ws += (size_t)NN * 4 * 4;
    float* ad_buf = (float*)ws;       ws += (size_t)NN * 4 * 4;
    int* cnt = (int*)ws;              ws += (size_t)NN * 4;
    int* rowptr = (int*)ws;           ws += (size_t)(NN + 64) * 4;
    int* cursor = (int*)ws;           ws += (size_t)NN * 4;
    unsigned int* ep = (unsigned int*)ws; ws += (size_t)NE * 4;
    int* part = (int*)ws;             ws += 512 * 4;
    float* ce_buf = (float*)ws;       ws += 64 * 4;
    float* gbuf = (float*)ws;         ws += (size_t)NG * 50 * 4;

    // CSR build + per-layer edge constants
    hipMemsetAsync(cnt, 0, (size_t)NN * 4, stream);
    k_hist<<<NE / 256, 256, 0, stream>>>(dst, cnt);
    k_scan1<<<NN / 256, 256, 0, stream>>>(cnt, rowptr, part);
    k_scan2<<<1, 512, 0, stream>>>(part, We1, ae1, We2, ae2, We3, ae3, We4, ae4, ce_buf);
    k_scan3<<<NN / 256, 256, 0, stream>>>(rowptr, part, cursor);
    k_scatter<<<NE / 256, 256, 0, stream>>>(src, dst, ew, cursor, ep);

    // layer 1: fin=6, H=4, C=16 (F=64)
    k_transform<6, 64, 64, 64, 4, 16, 8><<<NN / 32, 256, 0, stream>>>(x, W1, as1, ad1, hbuf, as_buf, ad_buf);
    k_aggregate<4, 16, false><<<NN / 4, 256, 0, stream>>>(hbuf, as_buf, ad_buf, rowptr, ep, ce_buf,
                                                          b1, nullptr, nullptr, nullptr, nullptr, feat);
    // layer 2: fin=64, H=4, C=32 (F=128)
    k_transform<64, 128, 128, 128, 4, 32, 16><<<NN / 32, 256, 0, stream>>>(feat, W2, as2, ad2, hbuf, as_buf, ad_buf);
    k_aggregate<4, 32, false><<<NN / 4, 256, 0, stream>>>(hbuf, as_buf, ad_buf, rowptr, ep, ce_buf + 4,
                                                          b2, nullptr, nullptr, nullptr, nullptr, feat);
    // layer 3: fin=128, H=4, C=16 (F=64)
    k_transform<128, 64, 64, 64, 4, 16, 8><<<NN / 32, 256, 0, stream>>>(feat, W3, as3, ad3, hbuf, as_buf, ad_buf);
    k_aggregate<4, 16, false><<<NN / 4, 256, 0, stream>>>(hbuf, as_buf, ad_buf, rowptr, ep, ce_buf + 8,
                                                          b3, nullptr, nullptr, nullptr, nullptr, feat);
    // layer 4: fin=64, H=1, C=50 (F=50 padded to 64), fused bias+BN+lrelu, per-node out
    k_transform<64, 50, 64, 64, 1, 50, 8><<<NN / 32, 256, 0, stream>>>(feat, W4, as4, ad4, hbuf, as_buf, ad_buf);
    k_aggregate<1, 50, true><<<NN / 4, 256, 0, stream>>>(hbuf, as_buf, ad_buf, rowptr, ep, ce_buf + 12,
                                                         b4, bn_g, bn_b, bn_rm, bn_rv, feat);
    // graph pooling (sorted batch, binary search) + final MLP
    k_pool<<<NG / 4, 256, 0, stream>>>(feat, batch, gbuf);
    k_mlp<<<NG / 256, 256, 0, stream>>>(gbuf, Wf1, bf1, Wf2, bf2, Wf3, bf3, out);
}

// Round 7
// 1070.102 us; speedup vs baseline: 1.5214x; 1.1530x over previous
//
#include <hip/hip_runtime.h>
#include <hip/hip_fp16.h>
#include <math.h>

#define NN 131072
#define NE 2097152
#define NG 16384

__device__ __forceinline__ float lrelu(float x, float s) { return fmaxf(x, s * x); }

template <int H>
__device__ __forceinline__ float sel_h(const float* a, int hsel) {
    if constexpr (H == 1) return a[0];
    else return hsel == 0 ? a[0] : hsel == 1 ? a[1] : hsel == 2 ? a[2] : a[3];
}

// ---------------- CSR build ----------------
// hist also captures each edge's rank within its dst bucket (return of atomicAdd)
__global__ void k_hist(const int* __restrict__ dst, int* __restrict__ cnt, int* __restrict__ rank) {
    int e = blockIdx.x * 256 + threadIdx.x;
    rank[e] = atomicAdd(&cnt[dst[e]], 1);
}

__global__ void k_scan1(const int* __restrict__ cnt, int* __restrict__ rowptr, int* __restrict__ part) {
    __shared__ int s[256];
    int t = threadIdx.x;
    int i = blockIdx.x * 256 + t;
    int v = cnt[i];
    s[t] = v;
    __syncthreads();
    for (int off = 1; off < 256; off <<= 1) {
        int x = (t >= off) ? s[t - off] : 0;
        __syncthreads();
        s[t] += x;
        __syncthreads();
    }
    rowptr[i] = s[t] - v;  // exclusive
    if (t == 255) part[blockIdx.x] = s[255];
}

// scan of block partials + per-layer attention-edge constants ce[h] = dot(We[h], ae[h])
__global__ void k_scan2(int* part,
                        const float* __restrict__ We1, const float* __restrict__ ae1,
                        const float* __restrict__ We2, const float* __restrict__ ae2,
                        const float* __restrict__ We3, const float* __restrict__ ae3,
                        const float* __restrict__ We4, const float* __restrict__ ae4,
                        float* __restrict__ ceb) {
    __shared__ int s[512];
    int t = threadIdx.x;
    int v = part[t];
    s[t] = v;
    __syncthreads();
    for (int off = 1; off < 512; off <<= 1) {
        int x = (t >= off) ? s[t - off] : 0;
        __syncthreads();
        s[t] += x;
        __syncthreads();
    }
    part[t] = s[t] - v;  // exclusive
    if (t < 4) {
        float c = 0.f;
        for (int i = 0; i < 16; i++) c += We1[t * 16 + i] * ae1[t * 16 + i];
        ceb[t] = c;
    } else if (t < 8) {
        int h = t - 4;
        float c = 0.f;
        for (int i = 0; i < 32; i++) c += We2[h * 32 + i] * ae2[h * 32 + i];
        ceb[t] = c;
    } else if (t < 12) {
        int h = t - 8;
        float c = 0.f;
        for (int i = 0; i < 16; i++) c += We3[h * 16 + i] * ae3[h * 16 + i];
        ceb[t] = c;
    } else if (t == 12) {
        float c = 0.f;
        for (int i = 0; i < 50; i++) c += We4[i] * ae4[i];
        ceb[t] = c;
    }
}

__global__ void k_scan3(int* __restrict__ rowptr, const int* __restrict__ part) {
    int t = threadIdx.x;
    int i = blockIdx.x * 256 + t;
    rowptr[i] = rowptr[i] + part[blockIdx.x];
    if (i == 0) rowptr[NN] = NE;
}

// scatter edges into dst-sorted order (no atomics: position = rowptr[dst] + rank),
// packing (src, ew) into one uint: u = (src << 15) | round(ew * 32767)
__global__ void k_scatter(const int* __restrict__ src, const int* __restrict__ dst,
                          const float* __restrict__ ew, const int* __restrict__ rowptr,
                          const int* __restrict__ rank, unsigned int* __restrict__ ep) {
    int e = blockIdx.x * 256 + threadIdx.x;
    int d = dst[e];
    int p = rowptr[d] + rank[e];
    unsigned int s = (unsigned int)src[e];
    unsigned int q = (unsigned int)(ew[e] * 32767.f + 0.5f);
    __builtin_nontemporal_store((s << 15) | (q & 0x7fffu), &ep[p]);
}

__device__ __forceinline__ void ep_unpack(unsigned int u, int& s, float& w) {
    s = (int)(u >> 15);
    w = (float)(u & 0x7fffu) * (1.f / 32767.f);
}

// ---------------- node transform + fused alpha projections ----------------
template <int FIN, int F, int FP, int FSO, int H, int C, int ITER>
__global__ void k_transform(const float* __restrict__ in, const float* __restrict__ W,
                            const float* __restrict__ as_, const float* __restrict__ ad_,
                            __half* __restrict__ h, float* __restrict__ alpha_s,
                            float* __restrict__ alpha_d) {
    constexpr int BN = 256 / FP;
    constexpr int GRP = ((C & (C - 1)) == 0) ? C : 64;
    __shared__ float Wl[FIN * F];
    __shared__ float xl[BN * FIN];
    int t = threadIdx.x;
    for (int i = t; i < FIN * F; i += 256) Wl[i] = W[i];
    int nl = t / FP, f = t % FP;
    float asf = (f < F) ? as_[f] : 0.f;
    float adf = (f < F) ? ad_[f] : 0.f;
    for (int it = 0; it < ITER; ++it) {
        int nb = (blockIdx.x * ITER + it) * BN;
        __syncthreads();
        for (int i = t; i < BN * FIN; i += 256) xl[i] = in[(size_t)nb * FIN + i];
        __syncthreads();
        int n = nb + nl;
        float acc = 0.f;
        if (f < F) {
#pragma unroll
            for (int k = 0; k < FIN; k++) acc += xl[nl * FIN + k] * Wl[k * F + f];
            h[(size_t)n * FSO + f] = __float2half(acc);
        } else if (f < FSO) {
            h[(size_t)n * FSO + f] = __float2half(0.f);
        }
        float hs = acc * asf;
        float hd = acc * adf;
#pragma unroll
        for (int off = 1; off < GRP; off <<= 1) {
            hs += __shfl_xor(hs, off);
            hd += __shfl_xor(hd, off);
        }
        if ((f % GRP) == 0 && f < F) {
            alpha_s[(size_t)n * H + f / GRP] = hs;
            alpha_d[(size_t)n * H + f / GRP] = hd;
        }
    }
}

// ---------------- per-node softmax + aggregation (1 wave / node, 4 nodes / block) ----------------
// No max-pass (alpha O(1), clamped at 80). Phase 1: coalesced packed-edge loads.
// Phase 2: byte-offsets staged in LDS; F=128: 16 lanes/edge uint4, 4 edges/iter;
// F<=64: 8 lanes/edge uint4 (8 feat/lane), 8 edges/iter.
template <int H, int C, bool FINAL>
__global__ __launch_bounds__(256) void k_aggregate(
    const __half* __restrict__ h, const float* __restrict__ asrc, const float* __restrict__ adst,
    const int* __restrict__ rowptr, const unsigned int* __restrict__ ep,
    const float* __restrict__ ceb, const float* __restrict__ b,
    const float* __restrict__ bn_g, const float* __restrict__ bn_b,
    const float* __restrict__ bn_rm, const float* __restrict__ bn_rv,
    float* __restrict__ out) {
    constexpr int F = H * C;
    constexpr bool P2 = (F > 64);
    constexpr int FSB = P2 ? 256 : 128;  // h row stride in BYTES
    constexpr int EPI = P2 ? 4 : 8;      // edges per iteration
    __shared__ float lds_att[4][(64 + EPI) * H];
    __shared__ int lds_off[4][64 + EPI];

    int wid = threadIdx.x >> 6;
    int lane = threadIdx.x & 63;
    int n = blockIdx.x * 4 + wid;
    int r0 = __builtin_amdgcn_readfirstlane(rowptr[n]);
    int r1 = __builtin_amdgcn_readfirstlane(rowptr[n + 1]);
    int deg = r1 - r0;

    // per-head constants (uniform scalar loads)
    float ce[H], ad[H];
#pragma unroll
    for (int hh = 0; hh < H; hh++) ce[hh] = ceb[hh];
    if constexpr (H == 4) {
        float4 adv = ((const float4*)adst)[n];
        ad[0] = adv.x; ad[1] = adv.y; ad[2] = adv.z; ad[3] = adv.w;
    } else {
        ad[0] = adst[n];
    }

    // ---- phase 1: one edge per lane; exp(alpha) directly ----
    bool val = lane < deg;
    int s_l = 0;
    float w_l = 0.f;
    if (val) ep_unpack(ep[r0 + lane], s_l, w_l);
    float ex_l[H], psum[H];
    if constexpr (H == 4) {
        if (val) {
            float4 v4 = ((const float4*)asrc)[s_l];
            ex_l[0] = __expf(fminf(lrelu(v4.x + ad[0] + w_l * ce[0], 0.2f), 80.f));
            ex_l[1] = __expf(fminf(lrelu(v4.y + ad[1] + w_l * ce[1], 0.2f), 80.f));
            ex_l[2] = __expf(fminf(lrelu(v4.z + ad[2] + w_l * ce[2], 0.2f), 80.f));
            ex_l[3] = __expf(fminf(lrelu(v4.w + ad[3] + w_l * ce[3], 0.2f), 80.f));
        } else {
            ex_l[0] = ex_l[1] = ex_l[2] = ex_l[3] = 0.f;
        }
    } else {
        ex_l[0] = val ? __expf(fminf(lrelu(asrc[s_l] + ad[0] + w_l * ce[0], 0.2f), 80.f)) : 0.f;
    }
#pragma unroll
    for (int hh = 0; hh < H; hh++) psum[hh] = ex_l[hh];
    // overflow edges (deg > 64, rare): add into denom
    for (int r = r0 + 64 + lane; r < r1; r += 64) {
        int s;
        float w;
        ep_unpack(ep[r], s, w);
        if constexpr (H == 4) {
            float4 v4 = ((const float4*)asrc)[s];
            psum[0] += __expf(fminf(lrelu(v4.x + ad[0] + w * ce[0], 0.2f), 80.f));
            psum[1] += __expf(fminf(lrelu(v4.y + ad[1] + w * ce[1], 0.2f), 80.f));
            psum[2] += __expf(fminf(lrelu(v4.z + ad[2] + w * ce[2], 0.2f), 80.f));
            psum[3] += __expf(fminf(lrelu(v4.w + ad[3] + w * ce[3], 0.2f), 80.f));
        } else {
            psum[0] += __expf(fminf(lrelu(asrc[s] + ad[0] + w * ce[0], 0.2f), 80.f));
        }
    }
    float rden[H];
#pragma unroll
    for (int hh = 0; hh < H; hh++) {
        float v = psum[hh];
#pragma unroll
        for (int off = 32; off >= 1; off >>= 1) v += __shfl_xor(v, off);
        rden[hh] = 1.f / (v + 1e-16f);
    }

    // stage att = ex/den and row byte-offset in LDS (+ zero pad for unroll overrun)
    lds_off[wid][lane] = s_l * FSB;
#pragma unroll
    for (int hh = 0; hh < H; hh++) lds_att[wid][lane * H + hh] = ex_l[hh] * rden[hh];
    if (lane < EPI) lds_off[wid][64 + lane] = 0;
    if (lane < EPI * H) lds_att[wid][64 * H + lane] = 0.f;
    __syncthreads();

    int jn = deg < 64 ? deg : 64;
    const char* hb = (const char*)h;

    if constexpr (P2) {
        // F=128: 16 lanes/edge, 8 features (uint4) per lane, 4 edges/iter
        int flane = lane & 15;
        int grp = lane >> 4;
        int f0 = 8 * flane;
        int hsel = f0 >> 5;  // C=32
        float a[8];
#pragma unroll
        for (int i = 0; i < 8; i++) a[i] = 0.f;
#pragma unroll 4
        for (int j = 0; j < jn; j += EPI) {
            int je = j + grp;
            int off = lds_off[wid][je];
            float att = lds_att[wid][je * H + hsel];
            uint4 p = *(const uint4*)(hb + (size_t)(off + flane * 16));
            const __half2* hp = (const __half2*)&p;
#pragma unroll
            for (int i = 0; i < 4; i++) {
                a[2 * i] = fmaf(__low2float(hp[i]), att, a[2 * i]);
                a[2 * i + 1] = fmaf(__high2float(hp[i]), att, a[2 * i + 1]);
            }
        }
        if (deg > 64) {  // rare
            float rdensel = sel_h<H>(rden, hsel);
            for (int r = r0 + 64; r < r1; ++r) {
                unsigned int u = __builtin_amdgcn_readfirstlane(ep[r]);
                int s;
                float w;
                ep_unpack(u, s, w);
                float4 v4 = ((const float4*)asrc)[s];
                float aA[4];
                aA[0] = fminf(lrelu(v4.x + ad[0] + w * ce[0], 0.2f), 80.f);
                aA[1] = fminf(lrelu(v4.y + ad[1] + w * ce[1], 0.2f), 80.f);
                aA[2] = fminf(lrelu(v4.z + ad[2] + w * ce[2], 0.2f), 80.f);
                aA[3] = fminf(lrelu(v4.w + ad[3] + w * ce[3], 0.2f), 80.f);
                float att = __expf(sel_h<H>(aA, hsel)) * rdensel;
                att = (grp == 0) ? att : 0.f;
                uint4 p = *(const uint4*)(hb + (size_t)(s * FSB + flane * 16));
                const __half2* hp = (const __half2*)&p;
#pragma unroll
                for (int i = 0; i < 4; i++) {
                    a[2 * i] = fmaf(__low2float(hp[i]), att, a[2 * i]);
                    a[2 * i + 1] = fmaf(__high2float(hp[i]), att, a[2 * i + 1]);
                }
            }
        }
#pragma unroll
        for (int i = 0; i < 8; i++) {
            a[i] += __shfl_xor(a[i], 32);
            a[i] += __shfl_xor(a[i], 16);
        }
        if (lane < 16) {
            float4 o0, o1;
            o0.x = lrelu(a[0] + b[f0], 0.01f);
            o0.y = lrelu(a[1] + b[f0 + 1], 0.01f);
            o0.z = lrelu(a[2] + b[f0 + 2], 0.01f);
            o0.w = lrelu(a[3] + b[f0 + 3], 0.01f);
            o1.x = lrelu(a[4] + b[f0 + 4], 0.01f);
            o1.y = lrelu(a[5] + b[f0 + 5], 0.01f);
            o1.z = lrelu(a[6] + b[f0 + 6], 0.01f);
            o1.w = lrelu(a[7] + b[f0 + 7], 0.01f);
            ((float4*)out)[(size_t)n * 32 + 2 * flane] = o0;
            ((float4*)out)[(size_t)n * 32 + 2 * flane + 1] = o1;
        }
    } else {
        // F<=64: 8 lanes/edge, 8 features (uint4) per lane, 8 edges/iter
        int flane = lane & 7;
        int grp = lane >> 3;
        int f0 = 8 * flane;
        int hsel = (H == 1) ? 0 : (f0 >> 4);  // C=16
        float a[8];
#pragma unroll
        for (int i = 0; i < 8; i++) a[i] = 0.f;
#pragma unroll 4
        for (int j = 0; j < jn; j += EPI) {
            int je = j + grp;
            int off = lds_off[wid][je];
            float att = lds_att[wid][je * H + hsel];
            uint4 p = *(const uint4*)(hb + (size_t)(off + flane * 16));
            const __half2* hp = (const __half2*)&p;
#pragma unroll
            for (int i = 0; i < 4; i++) {
                a[2 * i] = fmaf(__low2float(hp[i]), att, a[2 * i]);
                a[2 * i + 1] = fmaf(__high2float(hp[i]), att, a[2 * i + 1]);
            }
        }
        if (deg > 64) {  // rare
            float rdensel = sel_h<H>(rden, hsel);
            for (int r = r0 + 64; r < r1; ++r) {
                unsigned int u = __builtin_amdgcn_readfirstlane(ep[r]);
                int s;
                float w;
                ep_unpack(u, s, w);
                float aA[H];
                if constexpr (H == 4) {
                    float4 v4 = ((const float4*)asrc)[s];
                    aA[0] = fminf(lrelu(v4.x + ad[0] + w * ce[0], 0.2f), 80.f);
                    aA[1] = fminf(lrelu(v4.y + ad[1] + w * ce[1], 0.2f), 80.f);
                    aA[2] = fminf(lrelu(v4.z + ad[2] + w * ce[2], 0.2f), 80.f);
                    aA[3] = fminf(lrelu(v4.w + ad[3] + w * ce[3], 0.2f), 80.f);
                } else {
                    aA[0] = fminf(lrelu(asrc[s] + ad[0] + w * ce[0], 0.2f), 80.f);
                }
                float att = __expf(sel_h<H>(aA, hsel)) * rdensel;
                att = (grp == 0) ? att : 0.f;
                uint4 p = *(const uint4*)(hb + (size_t)(s * FSB + flane * 16));
                const __half2* hp = (const __half2*)&p;
#pragma unroll
                for (int i = 0; i < 4; i++) {
                    a[2 * i] = fmaf(__low2float(hp[i]), att, a[2 * i]);
                    a[2 * i + 1] = fmaf(__high2float(hp[i]), att, a[2 * i + 1]);
                }
            }
        }
#pragma unroll
        for (int i = 0; i < 8; i++) {
            a[i] += __shfl_xor(a[i], 32);
            a[i] += __shfl_xor(a[i], 16);
            a[i] += __shfl_xor(a[i], 8);
        }
        if constexpr (FINAL) {
            if (lane < 7) {
                float o[8];
#pragma unroll
                for (int k = 0; k < 8; k++) {
                    int f = f0 + k;
                    if (f < 50) {
                        float v = a[k] + b[f];
                        v = (v - bn_rm[f]) * rsqrtf(bn_rv[f] + 1e-5f) * bn_g[f] + bn_b[f];
                        o[k] = lrelu(v, 0.01f);
                    } else {
                        o[k] = 0.f;
                    }
                }
                if (f0 < 48) {
                    ((float4*)(out + (size_t)n * 64 + f0))[0] = make_float4(o[0], o[1], o[2], o[3]);
                    ((float4*)(out + (size_t)n * 64 + f0))[1] = make_float4(o[4], o[5], o[6], o[7]);
                } else {
                    ((float2*)(out + (size_t)n * 64 + 48))[0] = make_float2(o[0], o[1]);
                }
            }
        } else {
            if (lane < 8) {
                float4 o0, o1;
                o0.x = lrelu(a[0] + b[f0], 0.01f);
                o0.y = lrelu(a[1] + b[f0 + 1], 0.01f);
                o0.z = lrelu(a[2] + b[f0 + 2], 0.01f);
                o0.w = lrelu(a[3] + b[f0 + 3], 0.01f);
                o1.x = lrelu(a[4] + b[f0 + 4], 0.01f);
                o1.y = lrelu(a[5] + b[f0 + 5], 0.01f);
                o1.z = lrelu(a[6] + b[f0 + 6], 0.01f);
                o1.w = lrelu(a[7] + b[f0 + 7], 0.01f);
                ((float4*)out)[(size_t)n * 16 + 2 * flane] = o0;
                ((float4*)out)[(size_t)n * 16 + 2 * flane + 1] = o1;
            }
        }
    }
}

// ---------------- graph pooling: segment-sum via sorted batch (binary search) ----------------
__global__ __launch_bounds__(256) void k_pool(const float* __restrict__ nodeout, const int* __restrict__ batch,
                                              float* __restrict__ gbuf) {
    int wid = threadIdx.x >> 6;
    int lane = threadIdx.x & 63;
    int g = blockIdx.x * 4 + wid;
    int lo = 0, hi = NN;
    while (lo < hi) {
        int mid = (lo + hi) >> 1;
        if (batch[mid] < g) lo = mid + 1; else hi = mid;
    }
    int s0 = lo;
    hi = NN;
    while (lo < hi) {
        int mid = (lo + hi) >> 1;
        if (batch[mid] < g + 1) lo = mid + 1; else hi = mid;
    }
    int s1 = lo;
    if (lane < 50) {
        float acc = 0.f;
        for (int n = s0; n < s1; ++n) acc += nodeout[(size_t)n * 64 + lane];
        gbuf[(size_t)g * 50 + lane] = acc;
    }
}

// ---------------- final MLP over graphs: 64 threads/block, 1 graph/thread, LDS-staged ----------------
__global__ __launch_bounds__(64) void k_mlp(const float* __restrict__ gbuf,
                      const float* __restrict__ Wf1, const float* __restrict__ bf1,
                      const float* __restrict__ Wf2, const float* __restrict__ bf2,
                      const float* __restrict__ Wf3, const float* __restrict__ bf3,
                      float* __restrict__ out) {
    __shared__ float W1[1500], W2[600], W3[40], B1[30], B2[20], B3[2];
    __shared__ float G[64 * 50];
    int t = threadIdx.x;
    for (int i = t; i < 1500; i += 64) W1[i] = Wf1[i];
    for (int i = t; i < 600; i += 64) W2[i] = Wf2[i];
    if (t < 40) W3[t] = Wf3[t];
    if (t < 30) B1[t] = bf1[t];
    if (t < 20) B2[t] = bf2[t];
    if (t < 2) B3[t] = bf3[t];
    int g0 = blockIdx.x * 64;
    for (int i = t; i < 64 * 50; i += 64) G[i] = gbuf[(size_t)g0 * 50 + i];
    __syncthreads();
    float gv[50];
#pragma unroll
    for (int i = 0; i < 50; i++) gv[i] = G[t * 50 + i];
    float h1[30];
#pragma unroll
    for (int j = 0; j < 30; j++) {
        float a = B1[j];
#pragma unroll
        for (int i = 0; i < 50; i++) a += gv[i] * W1[i * 30 + j];
        h1[j] = lrelu(a, 0.01f);
    }
    float h2[20];
#pragma unroll
    for (int j = 0; j < 20; j++) {
        float a = B2[j];
#pragma unroll
        for (int i = 0; i < 30; i++) a += h1[i] * W2[i * 20 + j];
        h2[j] = lrelu(a, 0.01f);
    }
    int g = g0 + t;
    float o0 = B3[0], o1 = B3[1];
#pragma unroll
    for (int i = 0; i < 20; i++) {
        o0 += h2[i] * W3[i * 2];
        o1 += h2[i] * W3[i * 2 + 1];
    }
    ((float2*)out)[g] = make_float2(o0, o1);
}

extern "C" void kernel_launch(void* const* d_in, const int* in_sizes, int n_in,
                              void* d_out, int out_size, void* d_ws, size_t ws_size,
                              hipStream_t stream) {
    const float* x = (const float*)d_in[0];
    const int* ei = (const int*)d_in[1];
    const float* ew = (const float*)d_in[2];
    const int* batch = (const int*)d_in[3];
    const float* W1 = (const float*)d_in[4];
    const float* as1 = (const float*)d_in[5];
    const float* ad1 = (const float*)d_in[6];
    const float* We1 = (const float*)d_in[7];
    const float* ae1 = (const float*)d_in[8];
    const float* b1 = (const float*)d_in[9];
    const float* W2 = (const float*)d_in[10];
    const float* as2 = (const float*)d_in[11];
    const float* ad2 = (const float*)d_in[12];
    const float* We2 = (const float*)d_in[13];
    const float* ae2 = (const float*)d_in[14];
    const float* b2 = (const float*)d_in[15];
    const float* W3 = (const float*)d_in[16];
    const float* as3 = (const float*)d_in[17];
    const float* ad3 = (const float*)d_in[18];
    const float* We3 = (const float*)d_in[19];
    const float* ae3 = (const float*)d_in[20];
    const float* b3 = (const float*)d_in[21];
    const float* W4 = (const float*)d_in[22];
    const float* as4 = (const float*)d_in[23];
    const float* ad4 = (const float*)d_in[24];
    const float* We4 = (const float*)d_in[25];
    const float* ae4 = (const float*)d_in[26];
    const float* b4 = (const float*)d_in[27];
    const float* bn_g = (const float*)d_in[28];
    const float* bn_b = (const float*)d_in[29];
    const float* bn_rm = (const float*)d_in[30];
    const float* bn_rv = (const float*)d_in[31];
    const float* Wf1 = (const float*)d_in[32];
    const float* bf1 = (const float*)d_in[33];
    const float* Wf2 = (const float*)d_in[34];
    const float* bf2 = (const float*)d_in[35];
    const float* Wf3 = (const float*)d_in[36];
    const float* bf3 = (const float*)d_in[37];
    float* out = (float*)d_out;

    const int* src = ei;
    const int* dst = ei + NE;

    // workspace layout
    char* ws = (char*)d_ws;
    float* feat = (float*)ws;         ws += (size_t)NN * 128 * 4;  // 64 MB
    __half* hbuf = (__half*)ws;       ws += (size_t)NN * 128 * 2;  // 32 MB
    float* as_buf = (float*)ws;       ws += (size_t)NN * 4 * 4;
    float* ad_buf = (float*)ws;       ws += (size_t)NN * 4 * 4;
    int* cnt = (int*)ws;              ws += (size_t)NN * 4;
    int* rowptr = (int*)ws;           ws += (size_t)(NN + 64) * 4;
    unsigned int* ep = (unsigned int*)ws; ws += (size_t)NE * 4;
    int* part = (int*)ws;             ws += 512 * 4;
    float* ce_buf = (float*)ws;       ws += 64 * 4;
    float* gbuf = (float*)ws;         ws += (size_t)NG * 50 * 4;
    // rank reuses hbuf (free until layer-1 transform, which runs after scatter)
    int* rank = (int*)hbuf;

    // CSR build + per-layer edge constants
    hipMemsetAsync(cnt, 0, (size_t)NN * 4, stream);
    k_hist<<<NE / 256, 256, 0, stream>>>(dst, cnt, rank);
    k_scan1<<<NN / 256, 256, 0, stream>>>(cnt, rowptr, part);
    k_scan2<<<1, 512, 0, stream>>>(part, We1, ae1, We2, ae2, We3, ae3, We4, ae4, ce_buf);
    k_scan3<<<NN / 256, 256, 0, stream>>>(rowptr, part);
    k_scatter<<<NE / 256, 256, 0, stream>>>(src, dst, ew, rowptr, rank, ep);

    // layer 1: fin=6, H=4, C=16 (F=64)
    k_transform<6, 64, 64, 64, 4, 16, 8><<<NN / 32, 256, 0, stream>>>(x, W1, as1, ad1, hbuf, as_buf, ad_buf);
    k_aggregate<4, 16, false><<<NN / 4, 256, 0, stream>>>(hbuf, as_buf, ad_buf, rowptr, ep, ce_buf,
                                                          b1, nullptr, nullptr, nullptr, nullptr, feat);
    // layer 2: fin=64, H=4, C=32 (F=128)
    k_transform<64, 128, 128, 128, 4, 32, 16><<<NN / 32, 256, 0, stream>>>(feat, W2, as2, ad2, hbuf, as_buf, ad_buf);
    k_aggregate<4, 32, false><<<NN / 4, 256, 0, stream>>>(hbuf, as_buf, ad_buf, rowptr, ep, ce_buf + 4,
                                                          b2, nullptr, nullptr, nullptr, nullptr, feat);
    // layer 3: fin=128, H=4, C=16 (F=64)
    k_transform<128, 64, 64, 64, 4, 16, 8><<<NN / 32, 256, 0, stream>>>(feat, W3, as3, ad3, hbuf, as_buf, ad_buf);
    k_aggregate<4, 16, false><<<NN / 4, 256, 0, stream>>>(hbuf, as_buf, ad_buf, rowptr, ep, ce_buf + 8,
                                                          b3, nullptr, nullptr, nullptr, nullptr, feat);
    // layer 4: fin=64, H=1, C=50 (F=50 padded to 64), fused bias+BN+lrelu, per-node out
    k_transform<64, 50, 64, 64, 1, 50, 8><<<NN / 32, 256, 0, stream>>>(feat, W4, as4, ad4, hbuf, as_buf, ad_buf);
    k_aggregate<1, 50, true><<<NN / 4, 256, 0, stream>>>(hbuf, as_buf, ad_buf, rowptr, ep, ce_buf + 12,
                                                         b4, bn_g, bn_b, bn_rm, bn_rv, feat);
    // graph pooling (sorted batch, binary search) + final MLP
    k_pool<<<NG / 4, 256, 0, stream>>>(feat, batch, gbuf);
    k_mlp<<<NG / 64, 64, 0, stream>>>(gbuf, Wf1, bf1, Wf2, bf2, Wf3, bf3, out);
}

// Round 8
// 889.676 us; speedup vs baseline: 1.8300x; 1.2028x over previous
//
#include <hip/hip_runtime.h>
#include <hip/hip_fp16.h>
#include <math.h>

#define NN 131072
#define NE 2097152
#define NG 16384

__device__ __forceinline__ float lrelu(float x, float s) { return fmaxf(x, s * x); }

template <int H>
__device__ __forceinline__ float sel_h(const float* a, int hsel) {
    if constexpr (H == 1) return a[0];
    else return hsel == 0 ? a[0] : hsel == 1 ? a[1] : hsel == 2 ? a[2] : a[3];
}

// ---------------- CSR build ----------------
// hist also captures each edge's rank within its dst bucket (return of atomicAdd)
__global__ void k_hist(const int* __restrict__ dst, int* __restrict__ cnt, int* __restrict__ rank) {
    int e = blockIdx.x * 256 + threadIdx.x;
    rank[e] = atomicAdd(&cnt[dst[e]], 1);
}

__global__ void k_scan1(const int* __restrict__ cnt, int* __restrict__ rowptr, int* __restrict__ part) {
    __shared__ int s[256];
    int t = threadIdx.x;
    int i = blockIdx.x * 256 + t;
    int v = cnt[i];
    s[t] = v;
    __syncthreads();
    for (int off = 1; off < 256; off <<= 1) {
        int x = (t >= off) ? s[t - off] : 0;
        __syncthreads();
        s[t] += x;
        __syncthreads();
    }
    rowptr[i] = s[t] - v;  // exclusive
    if (t == 255) part[blockIdx.x] = s[255];
}

// scan of block partials + per-layer attention-edge constants ce[h] = dot(We[h], ae[h])
__global__ void k_scan2(int* part,
                        const float* __restrict__ We1, const float* __restrict__ ae1,
                        const float* __restrict__ We2, const float* __restrict__ ae2,
                        const float* __restrict__ We3, const float* __restrict__ ae3,
                        const float* __restrict__ We4, const float* __restrict__ ae4,
                        float* __restrict__ ceb) {
    __shared__ int s[512];
    int t = threadIdx.x;
    int v = part[t];
    s[t] = v;
    __syncthreads();
    for (int off = 1; off < 512; off <<= 1) {
        int x = (t >= off) ? s[t - off] : 0;
        __syncthreads();
        s[t] += x;
        __syncthreads();
    }
    part[t] = s[t] - v;  // exclusive
    if (t < 4) {
        float c = 0.f;
        for (int i = 0; i < 16; i++) c += We1[t * 16 + i] * ae1[t * 16 + i];
        ceb[t] = c;
    } else if (t < 8) {
        int h = t - 4;
        float c = 0.f;
        for (int i = 0; i < 32; i++) c += We2[h * 32 + i] * ae2[h * 32 + i];
        ceb[t] = c;
    } else if (t < 12) {
        int h = t - 8;
        float c = 0.f;
        for (int i = 0; i < 16; i++) c += We3[h * 16 + i] * ae3[h * 16 + i];
        ceb[t] = c;
    } else if (t == 12) {
        float c = 0.f;
        for (int i = 0; i < 50; i++) c += We4[i] * ae4[i];
        ceb[t] = c;
    }
}

__global__ void k_scan3(int* __restrict__ rowptr, const int* __restrict__ part) {
    int t = threadIdx.x;
    int i = blockIdx.x * 256 + t;
    rowptr[i] = rowptr[i] + part[blockIdx.x];
    if (i == 0) rowptr[NN] = NE;
}

// scatter edges into dst-sorted order (no atomics: position = rowptr[dst] + rank),
// packing (src, ew) into one uint: u = (src << 15) | round(ew * 32767)
__global__ void k_scatter(const int* __restrict__ src, const int* __restrict__ dst,
                          const float* __restrict__ ew, const int* __restrict__ rowptr,
                          const int* __restrict__ rank, unsigned int* __restrict__ ep) {
    int e = blockIdx.x * 256 + threadIdx.x;
    int d = dst[e];
    int p = rowptr[d] + rank[e];
    unsigned int s = (unsigned int)src[e];
    unsigned int q = (unsigned int)(ew[e] * 32767.f + 0.5f);
    __builtin_nontemporal_store((s << 15) | (q & 0x7fffu), &ep[p]);
}

__device__ __forceinline__ void ep_unpack(unsigned int u, int& s, float& w) {
    s = (int)(u >> 15);
    w = (float)(u & 0x7fffu) * (1.f / 32767.f);
}

// ---------------- node transform + fused alpha projections (register-tiled GEMM) ----------------
// 64-node tile: W (FIN x F, zero-padded to F from FR) staged once; X staged transposed
// (stride 65, bank-conflict-free). Each thread: 4 nodes x TF features in registers.
// Per k: 1 x-float4 (broadcast) + TF/4 W-float4 -> 4*TF FMAs. alpha via shfl_xor.
template <int FIN, int F, int FR, int H, int C, int ITER>
__global__ __launch_bounds__(256) void k_transform(
    const float* __restrict__ in, const float* __restrict__ W,
    const float* __restrict__ as_, const float* __restrict__ ad_,
    __half* __restrict__ h, float* __restrict__ alpha_s, float* __restrict__ alpha_d) {
    constexpr int TF = F / 16;   // features per thread
    constexpr int XS = 65;       // Xl row stride (floats)
    __shared__ float Wl[FIN * F];
    __shared__ float Xl[FIN * XS];
    int t = threadIdx.x;
    int tfg = t & 15;   // feature group
    int ng = t >> 4;    // node group (0..15)
    int f0 = tfg * TF;

    for (int i = t; i < FIN * F; i += 256) {
        int ff = i % F;
        Wl[i] = (ff < FR) ? W[(i / F) * FR + ff] : 0.f;
    }
    float asf[TF], adf[TF];
#pragma unroll
    for (int j = 0; j < TF; j++) {
        bool v = (f0 + j) < FR;
        asf[j] = v ? as_[f0 + j] : 0.f;
        adf[j] = v ? ad_[f0 + j] : 0.f;
    }

    for (int it = 0; it < ITER; ++it) {
        int nb = (blockIdx.x * ITER + it) * 64;
        __syncthreads();
        for (int i = t; i < 64 * FIN; i += 256) {
            int nn = i / FIN, kk = i % FIN;
            Xl[kk * XS + nn] = in[(size_t)(nb + nn) * FIN + kk];
        }
        __syncthreads();

        float acc[4][TF];
#pragma unroll
        for (int i = 0; i < 4; i++)
#pragma unroll
            for (int j = 0; j < TF; j++) acc[i][j] = 0.f;

#pragma unroll 2
        for (int k = 0; k < FIN; ++k) {
            float4 xv = *(const float4*)&Xl[k * XS + ng * 4];
            float wv[TF];
#pragma unroll
            for (int j4 = 0; j4 < TF; j4 += 4) {
                float4 w4 = *(const float4*)&Wl[k * F + f0 + j4];
                wv[j4] = w4.x; wv[j4 + 1] = w4.y; wv[j4 + 2] = w4.z; wv[j4 + 3] = w4.w;
            }
            const float xs[4] = {xv.x, xv.y, xv.z, xv.w};
#pragma unroll
            for (int i = 0; i < 4; i++)
#pragma unroll
                for (int j = 0; j < TF; j++) acc[i][j] = fmaf(xs[i], wv[j], acc[i][j]);
        }

        // epilogue: h (fp16) + fused alpha projections
#pragma unroll
        for (int i = 0; i < 4; i++) {
            int n = nb + ng * 4 + i;
            __half hv[TF];
            float ps = 0.f, pd = 0.f;
#pragma unroll
            for (int j = 0; j < TF; j++) {
                hv[j] = __float2half(acc[i][j]);
                ps = fmaf(acc[i][j], asf[j], ps);
                pd = fmaf(acc[i][j], adf[j], pd);
            }
            if constexpr (TF == 4) {
                *(uint2*)(h + (size_t)n * F + f0) = *(uint2*)hv;
            } else {
                *(uint4*)(h + (size_t)n * F + f0) = *(uint4*)hv;
            }
            ps += __shfl_xor(ps, 1);
            pd += __shfl_xor(pd, 1);
            ps += __shfl_xor(ps, 2);
            pd += __shfl_xor(pd, 2);
            if constexpr (H == 1) {
                ps += __shfl_xor(ps, 4);
                pd += __shfl_xor(pd, 4);
                ps += __shfl_xor(ps, 8);
                pd += __shfl_xor(pd, 8);
                if (tfg == 0) {
                    alpha_s[n] = ps;
                    alpha_d[n] = pd;
                }
            } else {
                if ((tfg & 3) == 0) {
                    alpha_s[(size_t)n * H + (tfg >> 2)] = ps;
                    alpha_d[(size_t)n * H + (tfg >> 2)] = pd;
                }
            }
        }
    }
}

// ---------------- per-node softmax + aggregation (1 wave / node, 4 nodes / block) ----------------
template <int H, int C, bool FINAL>
__global__ __launch_bounds__(256) void k_aggregate(
    const __half* __restrict__ h, const float* __restrict__ asrc, const float* __restrict__ adst,
    const int* __restrict__ rowptr, const unsigned int* __restrict__ ep,
    const float* __restrict__ ceb, const float* __restrict__ b,
    const float* __restrict__ bn_g, const float* __restrict__ bn_b,
    const float* __restrict__ bn_rm, const float* __restrict__ bn_rv,
    float* __restrict__ out) {
    constexpr int F = H * C;
    constexpr bool P2 = (F > 64);
    constexpr int FSB = P2 ? 256 : 128;  // h row stride in BYTES
    constexpr int EPI = P2 ? 4 : 8;      // edges per iteration
    __shared__ float lds_att[4][(64 + EPI) * H];
    __shared__ int lds_off[4][64 + EPI];

    int wid = threadIdx.x >> 6;
    int lane = threadIdx.x & 63;
    int n = blockIdx.x * 4 + wid;
    int r0 = __builtin_amdgcn_readfirstlane(rowptr[n]);
    int r1 = __builtin_amdgcn_readfirstlane(rowptr[n + 1]);
    int deg = r1 - r0;

    float ce[H], ad[H];
#pragma unroll
    for (int hh = 0; hh < H; hh++) ce[hh] = ceb[hh];
    if constexpr (H == 4) {
        float4 adv = ((const float4*)adst)[n];
        ad[0] = adv.x; ad[1] = adv.y; ad[2] = adv.z; ad[3] = adv.w;
    } else {
        ad[0] = adst[n];
    }

    // ---- phase 1: one edge per lane; exp(alpha) directly ----
    bool val = lane < deg;
    int s_l = 0;
    float w_l = 0.f;
    if (val) ep_unpack(ep[r0 + lane], s_l, w_l);
    float ex_l[H], psum[H];
    if constexpr (H == 4) {
        if (val) {
            float4 v4 = ((const float4*)asrc)[s_l];
            ex_l[0] = __expf(fminf(lrelu(v4.x + ad[0] + w_l * ce[0], 0.2f), 80.f));
            ex_l[1] = __expf(fminf(lrelu(v4.y + ad[1] + w_l * ce[1], 0.2f), 80.f));
            ex_l[2] = __expf(fminf(lrelu(v4.z + ad[2] + w_l * ce[2], 0.2f), 80.f));
            ex_l[3] = __expf(fminf(lrelu(v4.w + ad[3] + w_l * ce[3], 0.2f), 80.f));
        } else {
            ex_l[0] = ex_l[1] = ex_l[2] = ex_l[3] = 0.f;
        }
    } else {
        ex_l[0] = val ? __expf(fminf(lrelu(asrc[s_l] + ad[0] + w_l * ce[0], 0.2f), 80.f)) : 0.f;
    }
#pragma unroll
    for (int hh = 0; hh < H; hh++) psum[hh] = ex_l[hh];
    for (int r = r0 + 64 + lane; r < r1; r += 64) {
        int s;
        float w;
        ep_unpack(ep[r], s, w);
        if constexpr (H == 4) {
            float4 v4 = ((const float4*)asrc)[s];
            psum[0] += __expf(fminf(lrelu(v4.x + ad[0] + w * ce[0], 0.2f), 80.f));
            psum[1] += __expf(fminf(lrelu(v4.y + ad[1] + w * ce[1], 0.2f), 80.f));
            psum[2] += __expf(fminf(lrelu(v4.z + ad[2] + w * ce[2], 0.2f), 80.f));
            psum[3] += __expf(fminf(lrelu(v4.w + ad[3] + w * ce[3], 0.2f), 80.f));
        } else {
            psum[0] += __expf(fminf(lrelu(asrc[s] + ad[0] + w * ce[0], 0.2f), 80.f));
        }
    }
    float rden[H];
#pragma unroll
    for (int hh = 0; hh < H; hh++) {
        float v = psum[hh];
#pragma unroll
        for (int off = 32; off >= 1; off >>= 1) v += __shfl_xor(v, off);
        rden[hh] = 1.f / (v + 1e-16f);
    }

    lds_off[wid][lane] = s_l * FSB;
#pragma unroll
    for (int hh = 0; hh < H; hh++) lds_att[wid][lane * H + hh] = ex_l[hh] * rden[hh];
    if (lane < EPI) lds_off[wid][64 + lane] = 0;
    if (lane < EPI * H) lds_att[wid][64 * H + lane] = 0.f;
    __syncthreads();

    int jn = deg < 64 ? deg : 64;
    const char* hb = (const char*)h;

    if constexpr (P2) {
        int flane = lane & 15;
        int grp = lane >> 4;
        int f0 = 8 * flane;
        int hsel = f0 >> 5;  // C=32
        float a[8];
#pragma unroll
        for (int i = 0; i < 8; i++) a[i] = 0.f;
#pragma unroll 4
        for (int j = 0; j < jn; j += EPI) {
            int je = j + grp;
            int off = lds_off[wid][je];
            float att = lds_att[wid][je * H + hsel];
            uint4 p = *(const uint4*)(hb + (size_t)(off + flane * 16));
            const __half2* hp = (const __half2*)&p;
#pragma unroll
            for (int i = 0; i < 4; i++) {
                a[2 * i] = fmaf(__low2float(hp[i]), att, a[2 * i]);
                a[2 * i + 1] = fmaf(__high2float(hp[i]), att, a[2 * i + 1]);
            }
        }
        if (deg > 64) {  // rare
            float rdensel = sel_h<H>(rden, hsel);
            for (int r = r0 + 64; r < r1; ++r) {
                unsigned int u = __builtin_amdgcn_readfirstlane(ep[r]);
                int s;
                float w;
                ep_unpack(u, s, w);
                float4 v4 = ((const float4*)asrc)[s];
                float aA[4];
                aA[0] = fminf(lrelu(v4.x + ad[0] + w * ce[0], 0.2f), 80.f);
                aA[1] = fminf(lrelu(v4.y + ad[1] + w * ce[1], 0.2f), 80.f);
                aA[2] = fminf(lrelu(v4.z + ad[2] + w * ce[2], 0.2f), 80.f);
                aA[3] = fminf(lrelu(v4.w + ad[3] + w * ce[3], 0.2f), 80.f);
                float att = __expf(sel_h<H>(aA, hsel)) * rdensel;
                att = (grp == 0) ? att : 0.f;
                uint4 p = *(const uint4*)(hb + (size_t)(s * FSB + flane * 16));
                const __half2* hp = (const __half2*)&p;
#pragma unroll
                for (int i = 0; i < 4; i++) {
                    a[2 * i] = fmaf(__low2float(hp[i]), att, a[2 * i]);
                    a[2 * i + 1] = fmaf(__high2float(hp[i]), att, a[2 * i + 1]);
                }
            }
        }
#pragma unroll
        for (int i = 0; i < 8; i++) {
            a[i] += __shfl_xor(a[i], 32);
            a[i] += __shfl_xor(a[i], 16);
        }
        if (lane < 16) {
            float4 o0, o1;
            o0.x = lrelu(a[0] + b[f0], 0.01f);
            o0.y = lrelu(a[1] + b[f0 + 1], 0.01f);
            o0.z = lrelu(a[2] + b[f0 + 2], 0.01f);
            o0.w = lrelu(a[3] + b[f0 + 3], 0.01f);
            o1.x = lrelu(a[4] + b[f0 + 4], 0.01f);
            o1.y = lrelu(a[5] + b[f0 + 5], 0.01f);
            o1.z = lrelu(a[6] + b[f0 + 6], 0.01f);
            o1.w = lrelu(a[7] + b[f0 + 7], 0.01f);
            ((float4*)out)[(size_t)n * 32 + 2 * flane] = o0;
            ((float4*)out)[(size_t)n * 32 + 2 * flane + 1] = o1;
        }
    } else {
        int flane = lane & 7;
        int grp = lane >> 3;
        int f0 = 8 * flane;
        int hsel = (H == 1) ? 0 : (f0 >> 4);  // C=16
        float a[8];
#pragma unroll
        for (int i = 0; i < 8; i++) a[i] = 0.f;
#pragma unroll 4
        for (int j = 0; j < jn; j += EPI) {
            int je = j + grp;
            int off = lds_off[wid][je];
            float att = lds_att[wid][je * H + hsel];
            uint4 p = *(const uint4*)(hb + (size_t)(off + flane * 16));
            const __half2* hp = (const __half2*)&p;
#pragma unroll
            for (int i = 0; i < 4; i++) {
                a[2 * i] = fmaf(__low2float(hp[i]), att, a[2 * i]);
                a[2 * i + 1] = fmaf(__high2float(hp[i]), att, a[2 * i + 1]);
            }
        }
        if (deg > 64) {  // rare
            float rdensel = sel_h<H>(rden, hsel);
            for (int r = r0 + 64; r < r1; ++r) {
                unsigned int u = __builtin_amdgcn_readfirstlane(ep[r]);
                int s;
                float w;
                ep_unpack(u, s, w);
                float aA[H];
                if constexpr (H == 4) {
                    float4 v4 = ((const float4*)asrc)[s];
                    aA[0] = fminf(lrelu(v4.x + ad[0] + w * ce[0], 0.2f), 80.f);
                    aA[1] = fminf(lrelu(v4.y + ad[1] + w * ce[1], 0.2f), 80.f);
                    aA[2] = fminf(lrelu(v4.z + ad[2] + w * ce[2], 0.2f), 80.f);
                    aA[3] = fminf(lrelu(v4.w + ad[3] + w * ce[3], 0.2f), 80.f);
                } else {
                    aA[0] = fminf(lrelu(asrc[s] + ad[0] + w * ce[0], 0.2f), 80.f);
                }
                float att = __expf(sel_h<H>(aA, hsel)) * rdensel;
                att = (grp == 0) ? att : 0.f;
                uint4 p = *(const uint4*)(hb + (size_t)(s * FSB + flane * 16));
                const __half2* hp = (const __half2*)&p;
#pragma unroll
                for (int i = 0; i < 4; i++) {
                    a[2 * i] = fmaf(__low2float(hp[i]), att, a[2 * i]);
                    a[2 * i + 1] = fmaf(__high2float(hp[i]), att, a[2 * i + 1]);
                }
            }
        }
#pragma unroll
        for (int i = 0; i < 8; i++) {
            a[i] += __shfl_xor(a[i], 32);
            a[i] += __shfl_xor(a[i], 16);
            a[i] += __shfl_xor(a[i], 8);
        }
        if constexpr (FINAL) {
            if (lane < 7) {
                float o[8];
#pragma unroll
                for (int k = 0; k < 8; k++) {
                    int f = f0 + k;
                    if (f < 50) {
                        float v = a[k] + b[f];
                        v = (v - bn_rm[f]) * rsqrtf(bn_rv[f] + 1e-5f) * bn_g[f] + bn_b[f];
                        o[k] = lrelu(v, 0.01f);
                    } else {
                        o[k] = 0.f;
                    }
                }
                if (f0 < 48) {
                    ((float4*)(out + (size_t)n * 64 + f0))[0] = make_float4(o[0], o[1], o[2], o[3]);
                    ((float4*)(out + (size_t)n * 64 + f0))[1] = make_float4(o[4], o[5], o[6], o[7]);
                } else {
                    ((float2*)(out + (size_t)n * 64 + 48))[0] = make_float2(o[0], o[1]);
                }
            }
        } else {
            if (lane < 8) {
                float4 o0, o1;
                o0.x = lrelu(a[0] + b[f0], 0.01f);
                o0.y = lrelu(a[1] + b[f0 + 1], 0.01f);
                o0.z = lrelu(a[2] + b[f0 + 2], 0.01f);
                o0.w = lrelu(a[3] + b[f0 + 3], 0.01f);
                o1.x = lrelu(a[4] + b[f0 + 4], 0.01f);
                o1.y = lrelu(a[5] + b[f0 + 5], 0.01f);
                o1.z = lrelu(a[6] + b[f0 + 6], 0.01f);
                o1.w = lrelu(a[7] + b[f0 + 7], 0.01f);
                ((float4*)out)[(size_t)n * 16 + 2 * flane] = o0;
                ((float4*)out)[(size_t)n * 16 + 2 * flane + 1] = o1;
            }
        }
    }
}

// ---------------- graph pooling: segment-sum via sorted batch (binary search) ----------------
__global__ __launch_bounds__(256) void k_pool(const float* __restrict__ nodeout, const int* __restrict__ batch,
                                              float* __restrict__ gbuf) {
    int wid = threadIdx.x >> 6;
    int lane = threadIdx.x & 63;
    int g = blockIdx.x * 4 + wid;
    int lo = 0, hi = NN;
    while (lo < hi) {
        int mid = (lo + hi) >> 1;
        if (batch[mid] < g) lo = mid + 1; else hi = mid;
    }
    int s0 = lo;
    hi = NN;
    while (lo < hi) {
        int mid = (lo + hi) >> 1;
        if (batch[mid] < g + 1) lo = mid + 1; else hi = mid;
    }
    int s1 = lo;
    if (lane < 50) {
        float acc = 0.f;
        for (int n = s0; n < s1; ++n) acc += nodeout[(size_t)n * 64 + lane];
        gbuf[(size_t)g * 50 + lane] = acc;
    }
}

// ---------------- final MLP over graphs: 64 threads/block, 1 graph/thread, LDS-staged ----------------
__global__ __launch_bounds__(64) void k_mlp(const float* __restrict__ gbuf,
                      const float* __restrict__ Wf1, const float* __restrict__ bf1,
                      const float* __restrict__ Wf2, const float* __restrict__ bf2,
                      const float* __restrict__ Wf3, const float* __restrict__ bf3,
                      float* __restrict__ out) {
    __shared__ float W1[1500], W2[600], W3[40], B1[30], B2[20], B3[2];
    __shared__ float G[64 * 50];
    int t = threadIdx.x;
    for (int i = t; i < 1500; i += 64) W1[i] = Wf1[i];
    for (int i = t; i < 600; i += 64) W2[i] = Wf2[i];
    if (t < 40) W3[t] = Wf3[t];
    if (t < 30) B1[t] = bf1[t];
    if (t < 20) B2[t] = bf2[t];
    if (t < 2) B3[t] = bf3[t];
    int g0 = blockIdx.x * 64;
    for (int i = t; i < 64 * 50; i += 64) G[i] = gbuf[(size_t)g0 * 50 + i];
    __syncthreads();
    float gv[50];
#pragma unroll
    for (int i = 0; i < 50; i++) gv[i] = G[t * 50 + i];
    float h1[30];
#pragma unroll
    for (int j = 0; j < 30; j++) {
        float a = B1[j];
#pragma unroll
        for (int i = 0; i < 50; i++) a += gv[i] * W1[i * 30 + j];
        h1[j] = lrelu(a, 0.01f);
    }
    float h2[20];
#pragma unroll
    for (int j = 0; j < 20; j++) {
        float a = B2[j];
#pragma unroll
        for (int i = 0; i < 30; i++) a += h1[i] * W2[i * 20 + j];
        h2[j] = lrelu(a, 0.01f);
    }
    int g = g0 + t;
    float o0 = B3[0], o1 = B3[1];
#pragma unroll
    for (int i = 0; i < 20; i++) {
        o0 += h2[i] * W3[i * 2];
        o1 += h2[i] * W3[i * 2 + 1];
    }
    ((float2*)out)[g] = make_float2(o0, o1);
}

extern "C" void kernel_launch(void* const* d_in, const int* in_sizes, int n_in,
                              void* d_out, int out_size, void* d_ws, size_t ws_size,
                              hipStream_t stream) {
    const float* x = (const float*)d_in[0];
    const int* ei = (const int*)d_in[1];
    const float* ew = (const float*)d_in[2];
    const int* batch = (const int*)d_in[3];
    const float* W1 = (const float*)d_in[4];
    const float* as1 = (const float*)d_in[5];
    const float* ad1 = (const float*)d_in[6];
    const float* We1 = (const float*)d_in[7];
    const float* ae1 = (const float*)d_in[8];
    const float* b1 = (const float*)d_in[9];
    const float* W2 = (const float*)d_in[10];
    const float* as2 = (const float*)d_in[11];
    const float* ad2 = (const float*)d_in[12];
    const float* We2 = (const float*)d_in[13];
    const float* ae2 = (const float*)d_in[14];
    const float* b2 = (const float*)d_in[15];
    const float* W3 = (const float*)d_in[16];
    const float* as3 = (const float*)d_in[17];
    const float* ad3 = (const float*)d_in[18];
    const float* We3 = (const float*)d_in[19];
    const float* ae3 = (const float*)d_in[20];
    const float* b3 = (const float*)d_in[21];
    const float* W4 = (const float*)d_in[22];
    const float* as4 = (const float*)d_in[23];
    const float* ad4 = (const float*)d_in[24];
    const float* We4 = (const float*)d_in[25];
    const float* ae4 = (const float*)d_in[26];
    const float* b4 = (const float*)d_in[27];
    const float* bn_g = (const float*)d_in[28];
    const float* bn_b = (const float*)d_in[29];
    const float* bn_rm = (const float*)d_in[30];
    const float* bn_rv = (const float*)d_in[31];
    const float* Wf1 = (const float*)d_in[32];
    const float* bf1 = (const float*)d_in[33];
    const float* Wf2 = (const float*)d_in[34];
    const float* bf2 = (const float*)d_in[35];
    const float* Wf3 = (const float*)d_in[36];
    const float* bf3 = (const float*)d_in[37];
    float* out = (float*)d_out;

    const int* src = ei;
    const int* dst = ei + NE;

    // workspace layout
    char* ws = (char*)d_ws;
    float* feat = (float*)ws;         ws += (size_t)NN * 128 * 4;  // 64 MB
    __half* hbuf = (__half*)ws;       ws += (size_t)NN * 128 * 2;  // 32 MB
    float* as_buf = (float*)ws;       ws += (size_t)NN * 4 * 4;
    float* ad_buf = (float*)ws;       ws += (size_t)NN * 4 * 4;
    int* cnt = (int*)ws;              ws += (size_t)NN * 4;
    int* rowptr = (int*)ws;           ws += (size_t)(NN + 64) * 4;
    unsigned int* ep = (unsigned int*)ws; ws += (size_t)NE * 4;
    int* part = (int*)ws;             ws += 512 * 4;
    float* ce_buf = (float*)ws;       ws += 64 * 4;
    float* gbuf = (float*)ws;         ws += (size_t)NG * 50 * 4;
    // rank reuses hbuf (free until layer-1 transform, which runs after scatter)
    int* rank = (int*)hbuf;

    // CSR build + per-layer edge constants
    hipMemsetAsync(cnt, 0, (size_t)NN * 4, stream);
    k_hist<<<NE / 256, 256, 0, stream>>>(dst, cnt, rank);
    k_scan1<<<NN / 256, 256, 0, stream>>>(cnt, rowptr, part);
    k_scan2<<<1, 512, 0, stream>>>(part, We1, ae1, We2, ae2, We3, ae3, We4, ae4, ce_buf);
    k_scan3<<<NN / 256, 256, 0, stream>>>(rowptr, part);
    k_scatter<<<NE / 256, 256, 0, stream>>>(src, dst, ew, rowptr, rank, ep);

    // layer 1: fin=6, H=4, C=16 (F=64)
    k_transform<6, 64, 64, 4, 16, 4><<<NN / 256, 256, 0, stream>>>(x, W1, as1, ad1, hbuf, as_buf, ad_buf);
    k_aggregate<4, 16, false><<<NN / 4, 256, 0, stream>>>(hbuf, as_buf, ad_buf, rowptr, ep, ce_buf,
                                                          b1, nullptr, nullptr, nullptr, nullptr, feat);
    // layer 2: fin=64, H=4, C=32 (F=128)
    k_transform<64, 128, 128, 4, 32, 4><<<NN / 256, 256, 0, stream>>>(feat, W2, as2, ad2, hbuf, as_buf, ad_buf);
    k_aggregate<4, 32, false><<<NN / 4, 256, 0, stream>>>(hbuf, as_buf, ad_buf, rowptr, ep, ce_buf + 4,
                                                          b2, nullptr, nullptr, nullptr, nullptr, feat);
    // layer 3: fin=128, H=4, C=16 (F=64)
    k_transform<128, 64, 64, 4, 16, 4><<<NN / 256, 256, 0, stream>>>(feat, W3, as3, ad3, hbuf, as_buf, ad_buf);
    k_aggregate<4, 16, false><<<NN / 4, 256, 0, stream>>>(hbuf, as_buf, ad_buf, rowptr, ep, ce_buf + 8,
                                                          b3, nullptr, nullptr, nullptr, nullptr, feat);
    // layer 4: fin=64, F padded 50->64, H=1, fused bias+BN+lrelu, per-node out
    k_transform<64, 64, 50, 1, 50, 4><<<NN / 256, 256, 0, stream>>>(feat, W4, as4, ad4, hbuf, as_buf, ad_buf);
    k_aggregate<1, 50, true><<<NN / 4, 256, 0, stream>>>(hbuf, as_buf, ad_buf, rowptr, ep, ce_buf + 12,
                                                         b4, bn_g, bn_b, bn_rm, bn_rv, feat);
    // graph pooling (sorted batch, binary search) + final MLP
    k_pool<<<NG / 4, 256, 0, stream>>>(feat, batch, gbuf);
    k_mlp<<<NG / 64, 64, 0, stream>>>(gbuf, Wf1, bf1, Wf2, bf2, Wf3, bf3, out);
}

// Round 9
// 788.158 us; speedup vs baseline: 2.0657x; 1.1288x over previous
//
#include <hip/hip_runtime.h>
#include <hip/hip_fp16.h>
#include <math.h>

#define NN 131072
#define NE 2097152
#define NG 16384

__device__ __forceinline__ float lrelu(float x, float s) { return fmaxf(x, s * x); }

template <int H>
__device__ __forceinline__ float sel_h(const float* a, int hsel) {
    if constexpr (H == 1) return a[0];
    else return hsel == 0 ? a[0] : hsel == 1 ? a[1] : hsel == 2 ? a[2] : a[3];
}

// ---------------- CSR build ----------------
__global__ void k_hist(const int* __restrict__ dst, int* __restrict__ cnt, int* __restrict__ rank) {
    int e = blockIdx.x * 256 + threadIdx.x;
    rank[e] = atomicAdd(&cnt[dst[e]], 1);
}

__global__ void k_scan1(const int* __restrict__ cnt, int* __restrict__ rowptr, int* __restrict__ part) {
    __shared__ int s[256];
    int t = threadIdx.x;
    int i = blockIdx.x * 256 + t;
    int v = cnt[i];
    s[t] = v;
    __syncthreads();
    for (int off = 1; off < 256; off <<= 1) {
        int x = (t >= off) ? s[t - off] : 0;
        __syncthreads();
        s[t] += x;
        __syncthreads();
    }
    rowptr[i] = s[t] - v;  // exclusive
    if (t == 255) part[blockIdx.x] = s[255];
}

// scan of block partials + per-layer attention-edge constants ce[h] = dot(We[h], ae[h])
__global__ void k_scan2(int* part,
                        const float* __restrict__ We1, const float* __restrict__ ae1,
                        const float* __restrict__ We2, const float* __restrict__ ae2,
                        const float* __restrict__ We3, const float* __restrict__ ae3,
                        const float* __restrict__ We4, const float* __restrict__ ae4,
                        float* __restrict__ ceb) {
    __shared__ int s[512];
    int t = threadIdx.x;
    int v = part[t];
    s[t] = v;
    __syncthreads();
    for (int off = 1; off < 512; off <<= 1) {
        int x = (t >= off) ? s[t - off] : 0;
        __syncthreads();
        s[t] += x;
        __syncthreads();
    }
    part[t] = s[t] - v;  // exclusive
    if (t < 4) {
        float c = 0.f;
        for (int i = 0; i < 16; i++) c += We1[t * 16 + i] * ae1[t * 16 + i];
        ceb[t] = c;
    } else if (t < 8) {
        int h = t - 4;
        float c = 0.f;
        for (int i = 0; i < 32; i++) c += We2[h * 32 + i] * ae2[h * 32 + i];
        ceb[t] = c;
    } else if (t < 12) {
        int h = t - 8;
        float c = 0.f;
        for (int i = 0; i < 16; i++) c += We3[h * 16 + i] * ae3[h * 16 + i];
        ceb[t] = c;
    } else if (t == 12) {
        float c = 0.f;
        for (int i = 0; i < 50; i++) c += We4[i] * ae4[i];
        ceb[t] = c;
    }
}

__global__ void k_scan3(int* __restrict__ rowptr, const int* __restrict__ part) {
    int t = threadIdx.x;
    int i = blockIdx.x * 256 + t;
    rowptr[i] = rowptr[i] + part[blockIdx.x];
    if (i == 0) rowptr[NN] = NE;
}

// scatter edges into dst-sorted order (no atomics), packing (src, ew) into one uint
__global__ void k_scatter(const int* __restrict__ src, const int* __restrict__ dst,
                          const float* __restrict__ ew, const int* __restrict__ rowptr,
                          const int* __restrict__ rank, unsigned int* __restrict__ ep) {
    int e = blockIdx.x * 256 + threadIdx.x;
    int d = dst[e];
    int p = rowptr[d] + rank[e];
    unsigned int s = (unsigned int)src[e];
    unsigned int q = (unsigned int)(ew[e] * 32767.f + 0.5f);
    __builtin_nontemporal_store((s << 15) | (q & 0x7fffu), &ep[p]);
}

__device__ __forceinline__ void ep_unpack(unsigned int u, int& s, float& w) {
    s = (int)(u >> 15);
    w = (float)(u & 0x7fffu) * (1.f / 32767.f);
}

// ---------------- node transform + fused alpha projections (register-tiled GEMM) ----------------
template <int FIN, int F, int FR, int H, int C, int ITER>
__global__ __launch_bounds__(256) void k_transform(
    const float* __restrict__ in, const float* __restrict__ W,
    const float* __restrict__ as_, const float* __restrict__ ad_,
    __half* __restrict__ h, float* __restrict__ alpha_s, float* __restrict__ alpha_d) {
    constexpr int TF = F / 16;   // features per thread
    constexpr int XS = 65;       // Xl row stride (floats)
    __shared__ float Wl[FIN * F];
    __shared__ float Xl[FIN * XS];
    int t = threadIdx.x;
    int tfg = t & 15;   // feature group
    int ng = t >> 4;    // node group (0..15)
    int f0 = tfg * TF;

    for (int i = t; i < FIN * F; i += 256) {
        int ff = i % F;
        Wl[i] = (ff < FR) ? W[(i / F) * FR + ff] : 0.f;
    }
    float asf[TF], adf[TF];
#pragma unroll
    for (int j = 0; j < TF; j++) {
        bool v = (f0 + j) < FR;
        asf[j] = v ? as_[f0 + j] : 0.f;
        adf[j] = v ? ad_[f0 + j] : 0.f;
    }

    for (int it = 0; it < ITER; ++it) {
        int nb = (blockIdx.x * ITER + it) * 64;
        __syncthreads();
        for (int i = t; i < 64 * FIN; i += 256) {
            int nn = i / FIN, kk = i % FIN;
            Xl[kk * XS + nn] = in[(size_t)(nb + nn) * FIN + kk];
        }
        __syncthreads();

        float acc[4][TF];
#pragma unroll
        for (int i = 0; i < 4; i++)
#pragma unroll
            for (int j = 0; j < TF; j++) acc[i][j] = 0.f;

#pragma unroll 2
        for (int k = 0; k < FIN; ++k) {
            float4 xv = *(const float4*)&Xl[k * XS + ng * 4];
            float wv[TF];
#pragma unroll
            for (int j4 = 0; j4 < TF; j4 += 4) {
                float4 w4 = *(const float4*)&Wl[k * F + f0 + j4];
                wv[j4] = w4.x; wv[j4 + 1] = w4.y; wv[j4 + 2] = w4.z; wv[j4 + 3] = w4.w;
            }
            const float xs[4] = {xv.x, xv.y, xv.z, xv.w};
#pragma unroll
            for (int i = 0; i < 4; i++)
#pragma unroll
                for (int j = 0; j < TF; j++) acc[i][j] = fmaf(xs[i], wv[j], acc[i][j]);
        }

        // epilogue: h (fp16) + fused alpha projections
#pragma unroll
        for (int i = 0; i < 4; i++) {
            int n = nb + ng * 4 + i;
            __half hv[TF];
            float ps = 0.f, pd = 0.f;
#pragma unroll
            for (int j = 0; j < TF; j++) {
                hv[j] = __float2half(acc[i][j]);
                ps = fmaf(acc[i][j], asf[j], ps);
                pd = fmaf(acc[i][j], adf[j], pd);
            }
            if constexpr (TF == 4) {
                *(uint2*)(h + (size_t)n * F + f0) = *(uint2*)hv;
            } else {
                *(uint4*)(h + (size_t)n * F + f0) = *(uint4*)hv;
            }
            ps += __shfl_xor(ps, 1);
            pd += __shfl_xor(pd, 1);
            ps += __shfl_xor(ps, 2);
            pd += __shfl_xor(pd, 2);
            if constexpr (H == 1) {
                ps += __shfl_xor(ps, 4);
                pd += __shfl_xor(pd, 4);
                ps += __shfl_xor(ps, 8);
                pd += __shfl_xor(pd, 8);
                if (tfg == 0) {
                    alpha_s[n] = ps;
                    alpha_d[n] = pd;
                }
            } else {
                if ((tfg & 3) == 0) {
                    alpha_s[(size_t)n * H + (tfg >> 2)] = ps;
                    alpha_d[(size_t)n * H + (tfg >> 2)] = pd;
                }
            }
        }
    }
}

// ---------------- per-node softmax + aggregation (2 nodes / wave, 8 nodes / block) ----------------
// Phase 1 on half-waves (deg<=32 fast path; deg>32 rare slow path).
// All 32 staging slots per node are always initialized (invalid -> att=0), so the
// phase-2 group loop can overrun the degree safely within the node's slot range.
template <int H, int C, bool FINAL>
__global__ __launch_bounds__(256) void k_aggregate(
    const __half* __restrict__ h, const float* __restrict__ asrc, const float* __restrict__ adst,
    const int* __restrict__ rowptr, const unsigned int* __restrict__ ep,
    const float* __restrict__ ceb, const float* __restrict__ b,
    const float* __restrict__ bn_g, const float* __restrict__ bn_b,
    const float* __restrict__ bn_rm, const float* __restrict__ bn_rv,
    float* __restrict__ out) {
    constexpr int F = H * C;
    constexpr bool P2 = (F > 64);
    constexpr int FSB = P2 ? 256 : 128;  // h row stride in BYTES
    __shared__ float lds_att[4][64 * H];
    __shared__ int lds_off[4][64];

    int wid = threadIdx.x >> 6;
    int lane = threadIdx.x & 63;
    int half = lane >> 5;
    int hl = lane & 31;
    int n = blockIdx.x * 8 + wid * 2 + half;
    int r0 = rowptr[n];
    int r1 = rowptr[n + 1];
    int deg = r1 - r0;

    float ce[H], ad[H];
#pragma unroll
    for (int hh = 0; hh < H; hh++) ce[hh] = ceb[hh];
    if constexpr (H == 4) {
        float4 adv = ((const float4*)adst)[n];
        ad[0] = adv.x; ad[1] = adv.y; ad[2] = adv.z; ad[3] = adv.w;
    } else {
        ad[0] = adst[n];
    }

    // ---- phase 1: one edge per lane (32 lanes per node) ----
    bool val = hl < deg;
    int s_l = 0;
    float w_l = 0.f;
    if (val) ep_unpack(ep[r0 + hl], s_l, w_l);
    float ex_l[H], psum[H];
    if constexpr (H == 4) {
        if (val) {
            float4 v4 = ((const float4*)asrc)[s_l];
            ex_l[0] = __expf(fminf(lrelu(v4.x + ad[0] + w_l * ce[0], 0.2f), 80.f));
            ex_l[1] = __expf(fminf(lrelu(v4.y + ad[1] + w_l * ce[1], 0.2f), 80.f));
            ex_l[2] = __expf(fminf(lrelu(v4.z + ad[2] + w_l * ce[2], 0.2f), 80.f));
            ex_l[3] = __expf(fminf(lrelu(v4.w + ad[3] + w_l * ce[3], 0.2f), 80.f));
        } else {
            ex_l[0] = ex_l[1] = ex_l[2] = ex_l[3] = 0.f;
        }
    } else {
        ex_l[0] = val ? __expf(fminf(lrelu(asrc[s_l] + ad[0] + w_l * ce[0], 0.2f), 80.f)) : 0.f;
    }
#pragma unroll
    for (int hh = 0; hh < H; hh++) psum[hh] = ex_l[hh];
    // overflow edges (deg > 32, rare): add into denom (per half-wave)
    for (int r = r0 + 32 + hl; r < r1; r += 32) {
        int s;
        float w;
        ep_unpack(ep[r], s, w);
        if constexpr (H == 4) {
            float4 v4 = ((const float4*)asrc)[s];
            psum[0] += __expf(fminf(lrelu(v4.x + ad[0] + w * ce[0], 0.2f), 80.f));
            psum[1] += __expf(fminf(lrelu(v4.y + ad[1] + w * ce[1], 0.2f), 80.f));
            psum[2] += __expf(fminf(lrelu(v4.z + ad[2] + w * ce[2], 0.2f), 80.f));
            psum[3] += __expf(fminf(lrelu(v4.w + ad[3] + w * ce[3], 0.2f), 80.f));
        } else {
            psum[0] += __expf(fminf(lrelu(asrc[s] + ad[0] + w * ce[0], 0.2f), 80.f));
        }
    }
    float rden[H];
#pragma unroll
    for (int hh = 0; hh < H; hh++) {
        float v = psum[hh];
#pragma unroll
        for (int off = 16; off >= 1; off >>= 1) v += __shfl_xor(v, off);  // half-wave reduce
        rden[hh] = 1.f / (v + 1e-16f);
    }

    // stage att = ex/den and row byte-offset in LDS (32 slots per node, all initialized)
    lds_off[wid][lane] = s_l * FSB;
#pragma unroll
    for (int hh = 0; hh < H; hh++) lds_att[wid][lane * H + hh] = ex_l[hh] * rden[hh];
    __syncthreads();

    int jn = deg < 32 ? deg : 32;
    int base = half * 32;
    const char* hb = (const char*)h;

    if constexpr (P2) {
        // F=128: 16 lanes/edge, 8 features (uint4) per lane, 2 edges/iter per node
        int flane = hl & 15;
        int grp = hl >> 4;
        int f0 = 8 * flane;
        int hsel = f0 >> 5;  // C=32
        float a[8];
#pragma unroll
        for (int i = 0; i < 8; i++) a[i] = 0.f;
#pragma unroll 4
        for (int j = 0; j < jn; j += 2) {
            int je = base + j + grp;
            int off = lds_off[wid][je];
            float att = lds_att[wid][je * H + hsel];
            uint4 p = *(const uint4*)(hb + (size_t)(off + flane * 16));
            const __half2* hp = (const __half2*)&p;
#pragma unroll
            for (int i = 0; i < 4; i++) {
                a[2 * i] = fmaf(__low2float(hp[i]), att, a[2 * i]);
                a[2 * i + 1] = fmaf(__high2float(hp[i]), att, a[2 * i + 1]);
            }
        }
        if (deg > 32) {  // rare
            float rdensel = sel_h<H>(rden, hsel);
            for (int r = r0 + 32; r < r1; ++r) {
                unsigned int u = ep[r];
                int s;
                float w;
                ep_unpack(u, s, w);
                float4 v4 = ((const float4*)asrc)[s];
                float aA[4];
                aA[0] = fminf(lrelu(v4.x + ad[0] + w * ce[0], 0.2f), 80.f);
                aA[1] = fminf(lrelu(v4.y + ad[1] + w * ce[1], 0.2f), 80.f);
                aA[2] = fminf(lrelu(v4.z + ad[2] + w * ce[2], 0.2f), 80.f);
                aA[3] = fminf(lrelu(v4.w + ad[3] + w * ce[3], 0.2f), 80.f);
                float att = __expf(sel_h<H>(aA, hsel)) * rdensel;
                att = (grp == 0) ? att : 0.f;
                uint4 p = *(const uint4*)(hb + (size_t)(s * FSB + flane * 16));
                const __half2* hp = (const __half2*)&p;
#pragma unroll
                for (int i = 0; i < 4; i++) {
                    a[2 * i] = fmaf(__low2float(hp[i]), att, a[2 * i]);
                    a[2 * i + 1] = fmaf(__high2float(hp[i]), att, a[2 * i + 1]);
                }
            }
        }
#pragma unroll
        for (int i = 0; i < 8; i++) a[i] += __shfl_xor(a[i], 16);
        if (hl < 16) {
            float4 o0, o1;
            o0.x = lrelu(a[0] + b[f0], 0.01f);
            o0.y = lrelu(a[1] + b[f0 + 1], 0.01f);
            o0.z = lrelu(a[2] + b[f0 + 2], 0.01f);
            o0.w = lrelu(a[3] + b[f0 + 3], 0.01f);
            o1.x = lrelu(a[4] + b[f0 + 4], 0.01f);
            o1.y = lrelu(a[5] + b[f0 + 5], 0.01f);
            o1.z = lrelu(a[6] + b[f0 + 6], 0.01f);
            o1.w = lrelu(a[7] + b[f0 + 7], 0.01f);
            ((float4*)out)[(size_t)n * 32 + 2 * flane] = o0;
            ((float4*)out)[(size_t)n * 32 + 2 * flane + 1] = o1;
        }
    } else {
        // F<=64: 8 lanes/edge, 8 features (uint4) per lane, 4 edges/iter per node
        int flane = hl & 7;
        int grp = hl >> 3;
        int f0 = 8 * flane;
        int hsel = (H == 1) ? 0 : (f0 >> 4);  // C=16
        float a[8];
#pragma unroll
        for (int i = 0; i < 8; i++) a[i] = 0.f;
#pragma unroll 4
        for (int j = 0; j < jn; j += 4) {
            int je = base + j + grp;
            int off = lds_off[wid][je];
            float att = lds_att[wid][je * H + hsel];
            uint4 p = *(const uint4*)(hb + (size_t)(off + flane * 16));
            const __half2* hp = (const __half2*)&p;
#pragma unroll
            for (int i = 0; i < 4; i++) {
                a[2 * i] = fmaf(__low2float(hp[i]), att, a[2 * i]);
                a[2 * i + 1] = fmaf(__high2float(hp[i]), att, a[2 * i + 1]);
            }
        }
        if (deg > 32) {  // rare
            float rdensel = sel_h<H>(rden, hsel);
            for (int r = r0 + 32; r < r1; ++r) {
                unsigned int u = ep[r];
                int s;
                float w;
                ep_unpack(u, s, w);
                float aA[H];
                if constexpr (H == 4) {
                    float4 v4 = ((const float4*)asrc)[s];
                    aA[0] = fminf(lrelu(v4.x + ad[0] + w * ce[0], 0.2f), 80.f);
                    aA[1] = fminf(lrelu(v4.y + ad[1] + w * ce[1], 0.2f), 80.f);
                    aA[2] = fminf(lrelu(v4.z + ad[2] + w * ce[2], 0.2f), 80.f);
                    aA[3] = fminf(lrelu(v4.w + ad[3] + w * ce[3], 0.2f), 80.f);
                } else {
                    aA[0] = fminf(lrelu(asrc[s] + ad[0] + w * ce[0], 0.2f), 80.f);
                }
                float att = __expf(sel_h<H>(aA, hsel)) * rdensel;
                att = (grp == 0) ? att : 0.f;
                uint4 p = *(const uint4*)(hb + (size_t)(s * FSB + flane * 16));
                const __half2* hp = (const __half2*)&p;
#pragma unroll
                for (int i = 0; i < 4; i++) {
                    a[2 * i] = fmaf(__low2float(hp[i]), att, a[2 * i]);
                    a[2 * i + 1] = fmaf(__high2float(hp[i]), att, a[2 * i + 1]);
                }
            }
        }
#pragma unroll
        for (int i = 0; i < 8; i++) {
            a[i] += __shfl_xor(a[i], 8);
            a[i] += __shfl_xor(a[i], 16);
        }
        if constexpr (FINAL) {
            if (hl < 7) {
                float o[8];
#pragma unroll
                for (int k = 0; k < 8; k++) {
                    int f = f0 + k;
                    if (f < 50) {
                        float v = a[k] + b[f];
                        v = (v - bn_rm[f]) * rsqrtf(bn_rv[f] + 1e-5f) * bn_g[f] + bn_b[f];
                        o[k] = lrelu(v, 0.01f);
                    } else {
                        o[k] = 0.f;
                    }
                }
                if (f0 < 48) {
                    ((float4*)(out + (size_t)n * 64 + f0))[0] = make_float4(o[0], o[1], o[2], o[3]);
                    ((float4*)(out + (size_t)n * 64 + f0))[1] = make_float4(o[4], o[5], o[6], o[7]);
                } else {
                    ((float2*)(out + (size_t)n * 64 + 48))[0] = make_float2(o[0], o[1]);
                }
            }
        } else {
            if (hl < 8) {
                float4 o0, o1;
                o0.x = lrelu(a[0] + b[f0], 0.01f);
                o0.y = lrelu(a[1] + b[f0 + 1], 0.01f);
                o0.z = lrelu(a[2] + b[f0 + 2], 0.01f);
                o0.w = lrelu(a[3] + b[f0 + 3], 0.01f);
                o1.x = lrelu(a[4] + b[f0 + 4], 0.01f);
                o1.y = lrelu(a[5] + b[f0 + 5], 0.01f);
                o1.z = lrelu(a[6] + b[f0 + 6], 0.01f);
                o1.w = lrelu(a[7] + b[f0 + 7], 0.01f);
                ((float4*)out)[(size_t)n * 16 + 2 * flane] = o0;
                ((float4*)out)[(size_t)n * 16 + 2 * flane + 1] = o1;
            }
        }
    }
}

// ---------------- graph pooling: segment-sum via sorted batch (binary search) ----------------
__global__ __launch_bounds__(256) void k_pool(const float* __restrict__ nodeout, const int* __restrict__ batch,
                                              float* __restrict__ gbuf) {
    int wid = threadIdx.x >> 6;
    int lane = threadIdx.x & 63;
    int g = blockIdx.x * 4 + wid;
    int lo = 0, hi = NN;
    while (lo < hi) {
        int mid = (lo + hi) >> 1;
        if (batch[mid] < g) lo = mid + 1; else hi = mid;
    }
    int s0 = lo;
    hi = NN;
    while (lo < hi) {
        int mid = (lo + hi) >> 1;
        if (batch[mid] < g + 1) lo = mid + 1; else hi = mid;
    }
    int s1 = lo;
    if (lane < 50) {
        float acc = 0.f;
        for (int n = s0; n < s1; ++n) acc += nodeout[(size_t)n * 64 + lane];
        gbuf[(size_t)g * 50 + lane] = acc;
    }
}

// ---------------- final MLP over graphs: 64 threads/block, 1 graph/thread, LDS-staged ----------------
__global__ __launch_bounds__(64) void k_mlp(const float* __restrict__ gbuf,
                      const float* __restrict__ Wf1, const float* __restrict__ bf1,
                      const float* __restrict__ Wf2, const float* __restrict__ bf2,
                      const float* __restrict__ Wf3, const float* __restrict__ bf3,
                      float* __restrict__ out) {
    __shared__ float W1[1500], W2[600], W3[40], B1[30], B2[20], B3[2];
    __shared__ float G[64 * 50];
    int t = threadIdx.x;
    for (int i = t; i < 1500; i += 64) W1[i] = Wf1[i];
    for (int i = t; i < 600; i += 64) W2[i] = Wf2[i];
    if (t < 40) W3[t] = Wf3[t];
    if (t < 30) B1[t] = bf1[t];
    if (t < 20) B2[t] = bf2[t];
    if (t < 2) B3[t] = bf3[t];
    int g0 = blockIdx.x * 64;
    for (int i = t; i < 64 * 50; i += 64) G[i] = gbuf[(size_t)g0 * 50 + i];
    __syncthreads();
    float gv[50];
#pragma unroll
    for (int i = 0; i < 50; i++) gv[i] = G[t * 50 + i];
    float h1[30];
#pragma unroll
    for (int j = 0; j < 30; j++) {
        float a = B1[j];
#pragma unroll
        for (int i = 0; i < 50; i++) a += gv[i] * W1[i * 30 + j];
        h1[j] = lrelu(a, 0.01f);
    }
    float h2[20];
#pragma unroll
    for (int j = 0; j < 20; j++) {
        float a = B2[j];
#pragma unroll
        for (int i = 0; i < 30; i++) a += h1[i] * W2[i * 20 + j];
        h2[j] = lrelu(a, 0.01f);
    }
    int g = g0 + t;
    float o0 = B3[0], o1 = B3[1];
#pragma unroll
    for (int i = 0; i < 20; i++) {
        o0 += h2[i] * W3[i * 2];
        o1 += h2[i] * W3[i * 2 + 1];
    }
    ((float2*)out)[g] = make_float2(o0, o1);
}

extern "C" void kernel_launch(void* const* d_in, const int* in_sizes, int n_in,
                              void* d_out, int out_size, void* d_ws, size_t ws_size,
                              hipStream_t stream) {
    const float* x = (const float*)d_in[0];
    const int* ei = (const int*)d_in[1];
    const float* ew = (const float*)d_in[2];
    const int* batch = (const int*)d_in[3];
    const float* W1 = (const float*)d_in[4];
    const float* as1 = (const float*)d_in[5];
    const float* ad1 = (const float*)d_in[6];
    const float* We1 = (const float*)d_in[7];
    const float* ae1 = (const float*)d_in[8];
    const float* b1 = (const float*)d_in[9];
    const float* W2 = (const float*)d_in[10];
    const float* as2 = (const float*)d_in[11];
    const float* ad2 = (const float*)d_in[12];
    const float* We2 = (const float*)d_in[13];
    const float* ae2 = (const float*)d_in[14];
    const float* b2 = (const float*)d_in[15];
    const float* W3 = (const float*)d_in[16];
    const float* as3 = (const float*)d_in[17];
    const float* ad3 = (const float*)d_in[18];
    const float* We3 = (const float*)d_in[19];
    const float* ae3 = (const float*)d_in[20];
    const float* b3 = (const float*)d_in[21];
    const float* W4 = (const float*)d_in[22];
    const float* as4 = (const float*)d_in[23];
    const float* ad4 = (const float*)d_in[24];
    const float* We4 = (const float*)d_in[25];
    const float* ae4 = (const float*)d_in[26];
    const float* b4 = (const float*)d_in[27];
    const float* bn_g = (const float*)d_in[28];
    const float* bn_b = (const float*)d_in[29];
    const float* bn_rm = (const float*)d_in[30];
    const float* bn_rv = (const float*)d_in[31];
    const float* Wf1 = (const float*)d_in[32];
    const float* bf1 = (const float*)d_in[33];
    const float* Wf2 = (const float*)d_in[34];
    const float* bf2 = (const float*)d_in[35];
    const float* Wf3 = (const float*)d_in[36];
    const float* bf3 = (const float*)d_in[37];
    float* out = (float*)d_out;

    const int* src = ei;
    const int* dst = ei + NE;

    // workspace layout
    char* ws = (char*)d_ws;
    float* feat = (float*)ws;         ws += (size_t)NN * 128 * 4;  // 64 MB
    __half* hbuf = (__half*)ws;       ws += (size_t)NN * 128 * 2;  // 32 MB
    float* as_buf = (float*)ws;       ws += (size_t)NN * 4 * 4;
    float* ad_buf = (float*)ws;       ws += (size_t)NN * 4 * 4;
    int* cnt = (int*)ws;              ws += (size_t)NN * 4;
    int* rowptr = (int*)ws;           ws += (size_t)(NN + 64) * 4;
    unsigned int* ep = (unsigned int*)ws; ws += (size_t)NE * 4;
    int* part = (int*)ws;             ws += 512 * 4;
    float* ce_buf = (float*)ws;       ws += 64 * 4;
    float* gbuf = (float*)ws;         ws += (size_t)NG * 50 * 4;
    // rank reuses hbuf (free until layer-1 transform, which runs after scatter)
    int* rank = (int*)hbuf;

    // CSR build + per-layer edge constants
    hipMemsetAsync(cnt, 0, (size_t)NN * 4, stream);
    k_hist<<<NE / 256, 256, 0, stream>>>(dst, cnt, rank);
    k_scan1<<<NN / 256, 256, 0, stream>>>(cnt, rowptr, part);
    k_scan2<<<1, 512, 0, stream>>>(part, We1, ae1, We2, ae2, We3, ae3, We4, ae4, ce_buf);
    k_scan3<<<NN / 256, 256, 0, stream>>>(rowptr, part);
    k_scatter<<<NE / 256, 256, 0, stream>>>(src, dst, ew, rowptr, rank, ep);

    // layer 1: fin=6, H=4, C=16 (F=64)
    k_transform<6, 64, 64, 4, 16, 4><<<NN / 256, 256, 0, stream>>>(x, W1, as1, ad1, hbuf, as_buf, ad_buf);
    k_aggregate<4, 16, false><<<NN / 8, 256, 0, stream>>>(hbuf, as_buf, ad_buf, rowptr, ep, ce_buf,
                                                          b1, nullptr, nullptr, nullptr, nullptr, feat);
    // layer 2: fin=64, H=4, C=32 (F=128)
    k_transform<64, 128, 128, 4, 32, 4><<<NN / 256, 256, 0, stream>>>(feat, W2, as2, ad2, hbuf, as_buf, ad_buf);
    k_aggregate<4, 32, false><<<NN / 8, 256, 0, stream>>>(hbuf, as_buf, ad_buf, rowptr, ep, ce_buf + 4,
                                                          b2, nullptr, nullptr, nullptr, nullptr, feat);
    // layer 3: fin=128, H=4, C=16 (F=64)
    k_transform<128, 64, 64, 4, 16, 4><<<NN / 256, 256, 0, stream>>>(feat, W3, as3, ad3, hbuf, as_buf, ad_buf);
    k_aggregate<4, 16, false><<<NN / 8, 256, 0, stream>>>(hbuf, as_buf, ad_buf, rowptr, ep, ce_buf + 8,
                                                          b3, nullptr, nullptr, nullptr, nullptr, feat);
    // layer 4: fin=64, F padded 50->64, H=1, fused bias+BN+lrelu, per-node out
    k_transform<64, 64, 50, 1, 50, 4><<<NN / 256, 256, 0, stream>>>(feat, W4, as4, ad4, hbuf, as_buf, ad_buf);
    k_aggregate<1, 50, true><<<NN / 8, 256, 0, stream>>>(hbuf, as_buf, ad_buf, rowptr, ep, ce_buf + 12,
                                                         b4, bn_g, bn_b, bn_rm, bn_rv, feat);
    // graph pooling (sorted batch, binary search) + final MLP
    k_pool<<<NG / 4, 256, 0, stream>>>(feat, batch, gbuf);
    k_mlp<<<NG / 64, 64, 0, stream>>>(gbuf, Wf1, bf1, Wf2, bf2, Wf3, bf3, out);
}